// Round 3
// baseline (518.922 us; speedup 1.0000x reference)
//
#include <hip/hip_runtime.h>

#define BATCH 2
#define SEQL 2048
#define DM 1024
#define DSTATE 128
#define HD 64
#define CHUNK 256
#define DI 2048
#define NHEADS 32
#define CONVD 2304
#define DPROJ 4384
#define DPROJ_PAD 4608
#define DFF 4096
#define NC 8
#define ROWS (BATCH*SEQL)

typedef unsigned short ushort_t;
typedef short bf16x8 __attribute__((ext_vector_type(8)));
typedef float f32x4 __attribute__((ext_vector_type(4)));

__device__ __forceinline__ float softplus_f(float v){
    return (v > 20.f) ? v : log1pf(expf(v));
}
__device__ __forceinline__ float silu_f(float v){
    return v / (1.f + expf(-v));
}
__device__ __forceinline__ ushort_t f2b(float v){
    union { float f; unsigned int u; } x; x.f = v;
    unsigned int r = x.u + 0x7fffu + ((x.u >> 16) & 1u);
    return (ushort_t)(r >> 16);
}
__device__ __forceinline__ float b2f(ushort_t v){
    union { unsigned int u; float f; } x; x.u = ((unsigned int)v) << 16;
    return x.f;
}

// ================================================================ MFMA GEMM (legacy 128-row tile)
// C[M,N] = A[M,K](bf16) @ Bt[N,K](bf16)^T + bias. BM=128, BN=TN, BK=64.
// 32 KiB LDS -> 4-5 blocks/CU: inter-block overlap hides epilogue/staging.
// Used for: in-proj tail (N=288, DTX sidecar), out-proj & fc2 (fp32 split-K=2).
template<int ACT, int OUT_BF16, int TN, int NS, int DTX>
__global__ __launch_bounds__(256) void mfma_gemm_k(
    const ushort_t* __restrict__ A, const ushort_t* __restrict__ Bt,
    const float* __restrict__ bias, float* __restrict__ Cf,
    ushort_t* __restrict__ Cb, float* __restrict__ dtaux,
    int M, int N, int K, int ldc)
{
    constexpr int NT = (TN == 128) ? 4 : 2;
    constexpr int BROWS = TN / 4;
    __shared__ ushort_t As[128*64];
    __shared__ ushort_t Bs[TN*64];
    int tid = threadIdx.x;
    int lane = tid & 63, wave = tid >> 6;
    int m0 = blockIdx.y * 128, n0 = blockIdx.x * TN;
    int Ks = K / NS;
    int kb = (NS > 1) ? blockIdx.z * Ks : 0;
    int wave_m = (TN==128) ? (wave >> 1)*64 : (wave & 1)*64;
    int wave_n = (TN==128) ? (wave & 1)*64 : (wave >> 1)*32;
    int lrow = lane >> 3;
    int lcol = ((lane & 7) ^ lrow) * 8;
    const ushort_t* Abase = A  + (size_t)(m0 + wave*32    + lrow)*K + lcol + kb;
    const ushort_t* Bbase = Bt + (size_t)(n0 + wave*BROWS + lrow)*K + lcol + kb;
    ushort_t* AsW = &As[(wave*32)*64];
    ushort_t* BsW = &Bs[(wave*BROWS)*64];
    f32x4 acc[4][NT];
    #pragma unroll
    for (int i=0;i<4;i++)
        #pragma unroll
        for (int j=0;j<NT;j++) acc[i][j] = (f32x4){0.f,0.f,0.f,0.f};
    int lm = lane & 15;
    int quad = lane >> 4;
    for (int k0 = 0; k0 < Ks; k0 += 64){
        #pragma unroll
        for (int j = 0; j < 4; j++)
            __builtin_amdgcn_global_load_lds(
                (const __attribute__((address_space(1))) void*)(Abase + (size_t)(j*8)*K + k0),
                (__attribute__((address_space(3))) void*)(AsW + j*8*64), 16, 0, 0);
        #pragma unroll
        for (int j = 0; j < BROWS/8; j++)
            __builtin_amdgcn_global_load_lds(
                (const __attribute__((address_space(1))) void*)(Bbase + (size_t)(j*8)*K + k0),
                (__attribute__((address_space(3))) void*)(BsW + j*8*64), 16, 0, 0);
        __syncthreads();
        #pragma unroll
        for (int kk = 0; kk < 64; kk += 32){
            int cb = kk >> 3;
            bf16x8 af[4], bfr[NT];
            #pragma unroll
            for (int mt=0; mt<4; mt++)
                af[mt] = *(const bf16x8*)&As[(wave_m + mt*16 + lm)*64 + (((cb + quad) ^ (lm & 7))*8)];
            #pragma unroll
            for (int nt=0; nt<NT; nt++)
                bfr[nt] = *(const bf16x8*)&Bs[(wave_n + nt*16 + lm)*64 + (((cb + quad) ^ (lm & 7))*8)];
            #pragma unroll
            for (int mt=0; mt<4; mt++)
                #pragma unroll
                for (int nt=0; nt<NT; nt++)
                    acc[mt][nt] = __builtin_amdgcn_mfma_f32_16x16x32_bf16(af[mt], bfr[nt], acc[mt][nt], 0, 0, 0);
        }
        __syncthreads();
    }
    float* Cfo = Cf + (size_t)((NS > 1) ? blockIdx.z : 0) * (size_t)M * ldc;
    int addb = (NS == 1) || (blockIdx.z == 0);
    int crow0 = m0 + wave_m + quad * 4;
    int ccol0 = n0 + wave_n + lm;
    #pragma unroll
    for (int mt=0; mt<4; mt++){
        #pragma unroll
        for (int nt=0; nt<NT; nt++){
            int col = ccol0 + nt*16;
            if (col < N){
                float bv = addb ? bias[col] : 0.f;
                #pragma unroll
                for (int r=0; r<4; r++){
                    int row = crow0 + mt*16 + r;
                    float v = acc[mt][nt][r] + bv;
                    if (ACT == 1){
                        float t = fminf(fmaxf(v + 3.f, 0.f), 6.f);
                        v = v * t * (1.f/6.f);
                    }
                    if (OUT_BF16){
                        Cb[(size_t)row*ldc + col] = f2b(v);
                        if (DTX && col >= N - NHEADS)
                            dtaux[(size_t)row*NHEADS + (col - (N - NHEADS))] = v;
                    } else {
                        Cfo[(size_t)row*ldc + col] = v;
                    }
                }
            }
        }
    }
}

// ================================================================ 256x256 8-phase GEMM
// C[M,N](bf16) = A[M,K](bf16) @ Bt[N,K](bf16)^T + bias.  BM=BN=256, BK=64.
// 8 waves (2M x 4N), 512 threads, 128 KiB LDS double-buffer, counted vmcnt.
// 1 block/CU: ONLY launch with grid == 256 blocks (exactly one residency
// round); any remainder costs a full extra T_block (~37 us) [measured r1/r2].
template<int ACT>
__global__ __launch_bounds__(512) void gemm256_k(
    const ushort_t* __restrict__ A, const ushort_t* __restrict__ Bt,
    const float* __restrict__ bias, ushort_t* __restrict__ Cb,
    int M, int N, int K, int ldc, int nbx)
{
    __shared__ ushort_t sm[65536];          // 128 KiB
    const int tid  = threadIdx.x;
    const int lane = tid & 63, wave = tid >> 6;
    const int lm   = lane & 15, quad = lane >> 4;
    const int wm   = wave >> 2, wn = wave & 3;
    // XCD-aware bijective swizzle (gridDim.x % 8 == 0 by construction)
    const int nwg = gridDim.x;
    const int cpx = nwg >> 3;
    const int swz = (blockIdx.x & 7)*cpx + (blockIdx.x >> 3);
    const int bx = swz % nbx, by = swz / nbx;
    const int m0 = by << 8, n0 = bx << 8;
    const int NT  = K >> 6;
    // staging: thread t -> row t/4 (and +128), source granule pre-XOR'd
    const int srow = tid >> 2;
    const int scol = (((tid & 3) ^ ((srow >> 1) & 3)) << 3);
    const ushort_t* pA = A  + (size_t)(m0 + srow)*K + scol;
    const ushort_t* pB = Bt + (size_t)(n0 + srow)*K + scol;
    const size_t rstep = (size_t)128 * K;
    // ds_read bases
    const int swz8 = ((quad ^ ((lm >> 1) & 3)) << 3);
    const int aoff = (wm*128 + lm)*32 + swz8;
    const int boff = 16384 + (wn*64 + lm)*32 + swz8;

#define GL(off, src) __builtin_amdgcn_global_load_lds( \
        (const __attribute__((address_space(1))) void*)(src), \
        (__attribute__((address_space(3))) void*)(&sm[off]), 16, 0, 0)

    // -------- prologue: stage K-tile 0 into buf 0, drain, barrier
    {
        const int d = wave*512;
        GL(d,                 pA);        GL(d + 4096,          pA + rstep);
        GL(d + 16384,         pB);        GL(d + 16384 + 4096,  pB + rstep);
        GL(d + 8192,          pA + 32);   GL(d + 8192 + 4096,   pA + 32 + rstep);
        GL(d + 24576,         pB + 32);   GL(d + 24576 + 4096,  pB + 32 + rstep);
    }
    asm volatile("s_waitcnt vmcnt(0)" ::: "memory");
    __builtin_amdgcn_sched_barrier(0);
    __builtin_amdgcn_s_barrier();

    f32x4 acc[8][4];
    #pragma unroll
    for (int i = 0; i < 8; i++)
        #pragma unroll
        for (int j = 0; j < 4; j++) acc[i][j] = (f32x4){0.f,0.f,0.f,0.f};

#define MFMA16(MH) \
    __builtin_amdgcn_s_setprio(1); \
    _Pragma("unroll") \
    for (int mt = 0; mt < 4; mt++) \
        _Pragma("unroll") \
        for (int nt = 0; nt < 4; nt++) \
            acc[(MH)*4+mt][nt] = __builtin_amdgcn_mfma_f32_16x16x32_bf16(af[mt], bf[nt], acc[(MH)*4+mt][nt], 0, 0, 0); \
    __builtin_amdgcn_s_setprio(0);

    for (int t = 0; t < NT; ++t){
        const int bo = (t & 1) << 15;           // consume buffer
        const int nb = bo ^ 32768;              // prefetch buffer
        const bool stg = (t < NT-1);
        const ushort_t* pAn = pA + (size_t)(t+1)*64;
        const ushort_t* pBn = pB + (size_t)(t+1)*64;
        bf16x8 af[4], bf[4];

        // ---- P0: kk0, m-half 0   (8 ds_read; prefetch next A-kk0)
        #pragma unroll
        for (int nt = 0; nt < 4; nt++) bf[nt] = *(const bf16x8*)&sm[bo + boff + nt*512];
        #pragma unroll
        for (int mt = 0; mt < 4; mt++) af[mt] = *(const bf16x8*)&sm[bo + aoff + mt*512];
        if (stg){ GL(nb + wave*512, pAn); GL(nb + 4096 + wave*512, pAn + rstep); }
        __builtin_amdgcn_s_barrier();
        asm volatile("s_waitcnt lgkmcnt(0)");
        __builtin_amdgcn_sched_barrier(0);
        MFMA16(0)
        __builtin_amdgcn_s_barrier();

        // ---- P1: kk0, m-half 1   (4 ds_read; prefetch next B-kk0; wait cur-kk1)
        #pragma unroll
        for (int mt = 0; mt < 4; mt++) af[mt] = *(const bf16x8*)&sm[bo + aoff + 2048 + mt*512];
        if (stg){ GL(nb + 16384 + wave*512, pBn); GL(nb + 16384 + 4096 + wave*512, pBn + rstep); }
        if (stg) asm volatile("s_waitcnt vmcnt(4)" ::: "memory");
        else     asm volatile("s_waitcnt vmcnt(0)" ::: "memory");
        __builtin_amdgcn_sched_barrier(0);
        __builtin_amdgcn_s_barrier();
        asm volatile("s_waitcnt lgkmcnt(0)");
        __builtin_amdgcn_sched_barrier(0);
        MFMA16(1)
        __builtin_amdgcn_s_barrier();

        // ---- P2: kk1, m-half 1   (8 ds_read; prefetch next A-kk1)
        #pragma unroll
        for (int nt = 0; nt < 4; nt++) bf[nt] = *(const bf16x8*)&sm[bo + 8192 + boff + nt*512];
        #pragma unroll
        for (int mt = 0; mt < 4; mt++) af[mt] = *(const bf16x8*)&sm[bo + 8192 + aoff + 2048 + mt*512];
        if (stg){ GL(nb + 8192 + wave*512, pAn + 32); GL(nb + 8192 + 4096 + wave*512, pAn + 32 + rstep); }
        __builtin_amdgcn_s_barrier();
        asm volatile("s_waitcnt lgkmcnt(0)");
        __builtin_amdgcn_sched_barrier(0);
        MFMA16(1)
        __builtin_amdgcn_s_barrier();

        // ---- P3: kk1, m-half 0   (4 ds_read; prefetch next B-kk1; wait next-kk0)
        #pragma unroll
        for (int mt = 0; mt < 4; mt++) af[mt] = *(const bf16x8*)&sm[bo + 8192 + aoff + mt*512];
        if (stg){
            GL(nb + 24576 + wave*512, pBn + 32); GL(nb + 24576 + 4096 + wave*512, pBn + 32 + rstep);
            asm volatile("s_waitcnt vmcnt(4)" ::: "memory");
            __builtin_amdgcn_sched_barrier(0);
        }
        __builtin_amdgcn_s_barrier();
        asm volatile("s_waitcnt lgkmcnt(0)");
        __builtin_amdgcn_sched_barrier(0);
        MFMA16(0)
        __builtin_amdgcn_s_barrier();
    }
#undef MFMA16
#undef GL

    // -------- epilogue (bf16 out)
    const int crow = m0 + wm*128 + quad*4;
    const int ccol = n0 + wn*64 + lm;
    #pragma unroll
    for (int m8 = 0; m8 < 8; m8++){
        #pragma unroll
        for (int nt = 0; nt < 4; nt++){
            int col = ccol + nt*16;
            float bv = bias[col];
            #pragma unroll
            for (int r = 0; r < 4; r++){
                int row = crow + m8*16 + r;
                float v = acc[m8][nt][r] + bv;
                if (ACT == 1){
                    float tt = fminf(fmaxf(v + 3.f, 0.f), 6.f);
                    v = v * tt * (1.f/6.f);
                }
                Cb[(size_t)row*ldc + col] = f2b(v);
            }
        }
    }
}

// ---------------- merged: f2b(x) [blocks 0..16383] + W_in transpose [rest]
// W_in^T padded to DPROJ_PAD=4608 rows (zeros past DPROJ) so the in-proj
// tail GEMM can overread B rows 4384..4479 safely.
__global__ __launch_bounds__(256) void prep_in_k(const float* __restrict__ x,
                                                 ushort_t* __restrict__ x_bf,
                                                 const float* __restrict__ W_in,
                                                 ushort_t* __restrict__ WinT){
    __shared__ ushort_t tile[32][33];
    int bid = blockIdx.x;
    if (bid < 16384){
        int idx = bid*256 + threadIdx.x;
        x_bf[idx] = f2b(x[idx]);
        return;
    }
    int id2 = bid - 16384;                  // 4608 transpose blocks (144 x 32)
    int n0 = (id2 % 144)*32, k0 = (id2 / 144)*32;
    int tx = threadIdx.x & 31, ty = threadIdx.x >> 5;
    #pragma unroll
    for (int i = 0; i < 4; i++){
        int k = k0 + ty + i*8;
        int n = n0 + tx;
        float v = (n < DPROJ) ? W_in[(size_t)k*DPROJ + n] : 0.f;
        tile[ty + i*8][tx] = f2b(v);
    }
    __syncthreads();
    #pragma unroll
    for (int i = 0; i < 4; i++)
        WinT[(size_t)(n0 + ty + i*8)*DM + k0 + tx] = tile[tx][ty + i*8];
}

// ---------------- merged: W_out / fc1 / fc2 transposes in one launch
__global__ __launch_bounds__(256) void transpose3_k(const float* __restrict__ Wout,
                                                    const float* __restrict__ fc1w,
                                                    const float* __restrict__ fc2w,
                                                    ushort_t* __restrict__ WoutT,
                                                    ushort_t* __restrict__ fc1T,
                                                    ushort_t* __restrict__ fc2T){
    __shared__ ushort_t tile[32][33];
    int bid = blockIdx.x;
    const float* W; ushort_t* Wt; int K, N, gx, id;
    if (bid < 2048){        W = Wout; Wt = WoutT; K = DI;  N = DM;  gx = 32;  id = bid; }
    else if (bid < 6144){   W = fc1w; Wt = fc1T;  K = DM;  N = DFF; gx = 128; id = bid - 2048; }
    else {                  W = fc2w; Wt = fc2T;  K = DFF; N = DM;  gx = 32;  id = bid - 6144; }
    int n0 = (id % gx)*32, k0 = (id / gx)*32;
    int tx = threadIdx.x & 31, ty = threadIdx.x >> 5;
    #pragma unroll
    for (int i = 0; i < 4; i++){
        int k = k0 + ty + i*8;
        int n = n0 + tx;
        tile[ty + i*8][tx] = f2b(W[(size_t)k*N + n]);
    }
    __syncthreads();
    #pragma unroll
    for (int i = 0; i < 4; i++)
        Wt[(size_t)(n0 + ty + i*8)*K + k0 + tx] = tile[tx][ty + i*8];
}

// ---- merged: [0, 36864) depthwise conv+SiLU -> bf16; [36864, +512) dt-scan
#define CONVBLKS (ROWS*CONVD/256)
__global__ __launch_bounds__(256) void conv_dt_k(const ushort_t* __restrict__ zx,
                                                 const float* __restrict__ conv_w,
                                                 const float* __restrict__ conv_b,
                                                 ushort_t* __restrict__ convb,
                                                 const float* __restrict__ dtaux,
                                                 const float* __restrict__ time_diff,
                                                 const float* __restrict__ A_log,
                                                 const float* __restrict__ dt_bias,
                                                 const float* __restrict__ time_decay,
                                                 float* __restrict__ dtH,
                                                 float* __restrict__ Acum){
    __shared__ float s[CHUNK];
    int bid = blockIdx.x;
    if (bid < CONVBLKS){
        int idx = bid*256 + threadIdx.x;
        int c = idx % CONVD;
        int row = idx / CONVD;
        int t = row & (SEQL-1);
        float acc = conv_b[c];
        #pragma unroll
        for (int k = 0; k < 4; k++){
            int tt = t + k - 3;
            if (tt >= 0)
                acc += b2f(zx[((size_t)(row + k - 3))*DPROJ + DI + c]) * conv_w[c*4 + k];
        }
        convb[idx] = f2b(silu_f(acc));
        return;
    }
    int id2 = bid - CONVBLKS;                  // 512 dt blocks
    int c = id2 % NC;
    int h = (id2 / NC) % NHEADS;
    int b = id2 / (NC*NHEADS);
    int l = threadIdx.x;
    int t = c*CHUNK + l;
    float dtr = dtaux[((size_t)(b*SEQL + t))*NHEADS + h];
    float dtv = softplus_f(dtr + dt_bias[h]);
    float A = -expf(A_log[h]);
    float dA = dtv*A - softplus_f(time_decay[h]) * time_diff[b*SEQL + t];
    dtH[((size_t)(b*NHEADS + h))*SEQL + t] = dtv;        // [h][row] layout
    s[l] = dA;
    __syncthreads();
    for (int off = 1; off < CHUNK; off <<= 1){
        float v = (l >= off) ? s[l-off] : 0.f;
        __syncthreads();
        s[l] += v;
        __syncthreads();
    }
    Acum[((size_t)(b*NHEADS + h))*SEQL + t] = s[l];
}

// -------------------- MFMA G[b,c,l,s] = C_l . B_s (64x64x128), bf16 in/out
__global__ __launch_bounds__(256) void g_mfma_k(const ushort_t* __restrict__ convb,
                                                ushort_t* __restrict__ G){
    __shared__ ushort_t As[64*136];
    __shared__ ushort_t Bs[64*136];
    int bc = blockIdx.z;
    int l0 = blockIdx.y*64, s0 = blockIdx.x*64;
    int tid = threadIdx.x;
    int lane = tid & 63, wave = tid >> 6;
    int lm = lane & 15, quad = lane >> 4;
    const ushort_t* base = convb + (size_t)bc*CHUNK*CONVD;
    #pragma unroll
    for (int i = 0; i < 4; i++){
        int e = tid + i*256;
        int r = e >> 4, k = (e & 15)*8;
        *(bf16x8*)&As[r*136 + k] = *(const bf16x8*)&base[(size_t)(l0+r)*CONVD + DI + DSTATE + k];
        *(bf16x8*)&Bs[r*136 + k] = *(const bf16x8*)&base[(size_t)(s0+r)*CONVD + DI + k];
    }
    __syncthreads();
    f32x4 acc[4];
    #pragma unroll
    for (int j=0;j<4;j++) acc[j] = (f32x4){0.f,0.f,0.f,0.f};
    #pragma unroll
    for (int kk = 0; kk < 4; kk++){
        bf16x8 af = *(const bf16x8*)&As[(wave*16+lm)*136 + kk*32 + quad*8];
        #pragma unroll
        for (int nt = 0; nt < 4; nt++){
            bf16x8 bfr = *(const bf16x8*)&Bs[(nt*16+lm)*136 + kk*32 + quad*8];
            acc[nt] = __builtin_amdgcn_mfma_f32_16x16x32_bf16(af, bfr, acc[nt], 0, 0, 0);
        }
    }
    ushort_t* g = G + (size_t)bc*CHUNK*CHUNK;
    #pragma unroll
    for (int nt = 0; nt < 4; nt++)
        #pragma unroll
        for (int r = 0; r < 4; r++)
            g[(size_t)(l0 + wave*16 + quad*4 + r)*CHUNK + s0 + nt*16 + lm] = f2b(acc[nt][r]);
}

// ---- MFMA states[b,c,h,p,n] = sum_l B[l,n]*exp(AcL-Ac[l])*dt[l]*xs[l,p]
#define RSX 264
#define RSB 72
__global__ __launch_bounds__(256) void states_mfma_k(const ushort_t* __restrict__ convb,
                                                     const float* __restrict__ dtH,
                                                     const float* __restrict__ Acum,
                                                     float* __restrict__ states){
    __shared__ ushort_t xw[64*RSX];
    __shared__ ushort_t Bt[128*RSB];
    __shared__ float Acs[CHUNK];
    __shared__ float dts[CHUNK];
    int bid = blockIdx.x;
    int h = bid % NHEADS;
    int c = (bid / NHEADS) % NC;
    int b = bid / (NHEADS*NC);
    int tid = threadIdx.x;
    int lane = tid & 63, wave = tid >> 6;
    int lm = lane & 15, quad = lane >> 4;
    Acs[tid] = Acum[((size_t)(b*NHEADS + h))*SEQL + c*CHUNK + tid];
    dts[tid] = dtH[((size_t)(b*NHEADS + h))*SEQL + c*CHUNK + tid];
    __syncthreads();
    float AcL = Acs[CHUNK-1];
    {
        const ushort_t* xg = convb + ((size_t)(b*SEQL + c*CHUNK))*CONVD + h*HD;
        #pragma unroll
        for (int j8 = 0; j8 < 8; j8++){
            int s0 = wave*64 + j8*8;
            bf16x8 pk;
            #pragma unroll
            for (int j = 0; j < 8; j++){
                int l = s0 + j;
                pk[j] = (short)f2b(expf(AcL - Acs[l]) * dts[l] * b2f(xg[(size_t)l*CONVD + lane]));
            }
            *(bf16x8*)&xw[lane*RSX + s0] = pk;
        }
    }
    f32x4 acc[8];
    #pragma unroll
    for (int j=0;j<8;j++) acc[j] = (f32x4){0.f,0.f,0.f,0.f};
    const ushort_t* bbase = convb + ((size_t)(b*SEQL + c*CHUNK))*CONVD + DI;
    for (int l0 = 0; l0 < CHUNK; l0 += 64){
        __syncthreads();
        #pragma unroll
        for (int i = 0; i < 32; i++){
            int e = tid + i*256; int l = e >> 7, n = e & 127;
            Bt[n*RSB + l] = bbase[(size_t)(l0+l)*CONVD + n];
        }
        __syncthreads();
        #pragma unroll
        for (int kk = 0; kk < 2; kk++){
            bf16x8 af = *(const bf16x8*)&xw[(wave*16+lm)*RSX + l0 + kk*32 + quad*8];
            #pragma unroll
            for (int nt = 0; nt < 8; nt++){
                bf16x8 bfr = *(const bf16x8*)&Bt[(nt*16+lm)*RSB + kk*32 + quad*8];
                acc[nt] = __builtin_amdgcn_mfma_f32_16x16x32_bf16(af, bfr, acc[nt], 0, 0, 0);
            }
        }
    }
    float* outp = states + ((size_t)((b*NC + c)*NHEADS + h))*(HD*DSTATE);
    #pragma unroll
    for (int nt = 0; nt < 8; nt++)
        #pragma unroll
        for (int r = 0; r < 4; r++)
            outp[(size_t)(wave*16 + quad*4 + r)*DSTATE + nt*16 + lm] = acc[nt][r];
}

// ------------- inter-chunk recurrence, 16-way split over (p,n) elements
__global__ __launch_bounds__(256) void prev_scan_k(const float* __restrict__ states,
                                                   const float* __restrict__ Acum,
                                                   float* __restrict__ prev){
    int bid = blockIdx.x;                  // B*NHEADS*16
    int part = bid & 15;
    int h = (bid >> 4) & (NHEADS-1);
    int b = bid >> 9;
    int tid = threadIdx.x;
    const float* AcB = Acum + ((size_t)(b*NHEADS + h))*SEQL;
    float dec[NC];
    #pragma unroll
    for (int c = 0; c < NC; c++) dec[c] = expf(AcB[c*CHUNK + CHUNK-1]);
    #pragma unroll
    for (int j = 0; j < 2; j++){
        int e = part*512 + j*256 + tid;
        float carry = 0.f;
        #pragma unroll
        for (int c = 0; c < NC; c++){
            size_t idx = ((size_t)((b*NC + c)*NHEADS + h))*(HD*DSTATE) + e;
            prev[idx] = carry;
            carry = carry*dec[c] + states[idx];
        }
    }
}

// ===== MFMA SSD output: Y = P@(dt*xs) + (e^A C)@prev^T + D*xs  -> bf16 Ybf
#define RLX 264
#define RLP 136
__global__ __launch_bounds__(256) void y_mfma_k(const ushort_t* __restrict__ convb,
                                                const ushort_t* __restrict__ G,
                                                const float* __restrict__ Acum,
                                                const float* __restrict__ dtH,
                                                const float* __restrict__ prev,
                                                const float* __restrict__ Dp,
                                                ushort_t* __restrict__ Ybf){
    __shared__ ushort_t xdtT[64*RLX];
    __shared__ ushort_t prevs[64*RLP];
    __shared__ float Acs[CHUNK];
    __shared__ float dts[CHUNK];
    int bid = blockIdx.x;
    int h = bid % NHEADS;
    int c = (bid / NHEADS) % NC;
    int b = bid / (NHEADS*NC);
    int tid = threadIdx.x;
    int lane = tid & 63, wave = tid >> 6;
    int lm = lane & 15, quad = lane >> 4;

    Acs[tid] = Acum[((size_t)(b*NHEADS + h))*SEQL + c*CHUNK + tid];
    dts[tid] = dtH[((size_t)(b*NHEADS + h))*SEQL + c*CHUNK + tid];
    {
        const float* pv = prev + ((size_t)((b*NC + c)*NHEADS + h))*(HD*DSTATE);
        #pragma unroll
        for (int i = 0; i < 32; i++){
            int e = tid + i*256; int p = e >> 7, n = e & 127;
            prevs[p*RLP + n] = f2b(pv[e]);
        }
    }
    __syncthreads();
    {
        const ushort_t* xg = convb + ((size_t)(b*SEQL + c*CHUNK))*CONVD + h*HD;
        #pragma unroll
        for (int j8 = 0; j8 < 8; j8++){
            int s0 = wave*64 + j8*8;
            bf16x8 pk;
            #pragma unroll
            for (int j = 0; j < 8; j++){
                int l = s0 + j;
                pk[j] = (short)f2b(b2f(xg[(size_t)l*CONVD + lane]) * dts[l]);
            }
            *(bf16x8*)&xdtT[lane*RLX + s0] = pk;
        }
    }
    __syncthreads();

    int   lrow[4];  float Alr[4], eAlr[4];
    #pragma unroll
    for (int mt = 0; mt < 4; mt++){
        lrow[mt] = (mt*4 + wave)*16 + lm;
        Alr[mt]  = Acs[lrow[mt]];
        eAlr[mt] = expf(Alr[mt]);
    }
    const ushort_t* Gbase = G + ((size_t)(b*NC + c))*(CHUNK*CHUNK);

    f32x4 acc[4][4];
    #pragma unroll
    for (int i=0;i<4;i++)
        #pragma unroll
        for (int j=0;j<4;j++) acc[i][j] = (f32x4){0.f,0.f,0.f,0.f};

    for (int ks = 0; ks < 8; ks++){
        bf16x8 bfr[4];
        #pragma unroll
        for (int nt = 0; nt < 4; nt++)
            bfr[nt] = *(const bf16x8*)&xdtT[(nt*16+lm)*RLX + ks*32 + quad*8];
        #pragma unroll
        for (int mt = 0; mt < 4; mt++){
            int rblk = mt*4 + wave;
            int nst = rblk/2 + 1;
            if (ks < nst){
                int sbase = ks*32 + quad*8;
                bf16x8 g8 = *(const bf16x8*)&Gbase[(size_t)lrow[mt]*CHUNK + sbase];
                const float4* A4 = (const float4*)(&Acs[sbase]);
                float4 a0 = A4[0], a1 = A4[1];
                float Al = Alr[mt]; int l = lrow[mt];
                float pv[8];
                pv[0] = (sbase+0 <= l) ? b2f((ushort_t)g8[0])*expf(Al - a0.x) : 0.f;
                pv[1] = (sbase+1 <= l) ? b2f((ushort_t)g8[1])*expf(Al - a0.y) : 0.f;
                pv[2] = (sbase+2 <= l) ? b2f((ushort_t)g8[2])*expf(Al - a0.z) : 0.f;
                pv[3] = (sbase+3 <= l) ? b2f((ushort_t)g8[3])*expf(Al - a0.w) : 0.f;
                pv[4] = (sbase+4 <= l) ? b2f((ushort_t)g8[4])*expf(Al - a1.x) : 0.f;
                pv[5] = (sbase+5 <= l) ? b2f((ushort_t)g8[5])*expf(Al - a1.y) : 0.f;
                pv[6] = (sbase+6 <= l) ? b2f((ushort_t)g8[6])*expf(Al - a1.z) : 0.f;
                pv[7] = (sbase+7 <= l) ? b2f((ushort_t)g8[7])*expf(Al - a1.w) : 0.f;
                bf16x8 af;
                #pragma unroll
                for (int j = 0; j < 8; j++) af[j] = (short)f2b(pv[j]);
                #pragma unroll
                for (int nt = 0; nt < 4; nt++)
                    acc[mt][nt] = __builtin_amdgcn_mfma_f32_16x16x32_bf16(af, bfr[nt], acc[mt][nt], 0, 0, 0);
            }
        }
    }
    for (int kc = 0; kc < 4; kc++){
        bf16x8 bfr[4];
        #pragma unroll
        for (int nt = 0; nt < 4; nt++)
            bfr[nt] = *(const bf16x8*)&prevs[(nt*16+lm)*RLP + kc*32 + quad*8];
        #pragma unroll
        for (int mt = 0; mt < 4; mt++){
            int rowg = b*SEQL + c*CHUNK + lrow[mt];
            bf16x8 c8 = *(const bf16x8*)&convb[(size_t)rowg*CONVD + DI + DSTATE + kc*32 + quad*8];
            float e = eAlr[mt];
            bf16x8 af;
            #pragma unroll
            for (int j = 0; j < 8; j++) af[j] = (short)f2b(e * b2f((ushort_t)c8[j]));
            #pragma unroll
            for (int nt = 0; nt < 4; nt++)
                acc[mt][nt] = __builtin_amdgcn_mfma_f32_16x16x32_bf16(af, bfr[nt], acc[mt][nt], 0, 0, 0);
        }
    }
    float Dv = Dp[h];
    #pragma unroll
    for (int mt = 0; mt < 4; mt++){
        int l0 = (mt*4 + wave)*16 + quad*4;
        #pragma unroll
        for (int nt = 0; nt < 4; nt++){
            int p = nt*16 + lm;
            #pragma unroll
            for (int r = 0; r < 4; r++){
                int rowg = b*SEQL + c*CHUNK + l0 + r;
                float xs = b2f(convb[(size_t)rowg*CONVD + h*HD + p]);
                Ybf[(size_t)rowg*DI + h*HD + p] = f2b(acc[mt][nt][r] + Dv*xs);
            }
        }
    }
}

// ------------------------------- y = Y*silu(z); RMSNorm; * rms_w ; -> bf16
__global__ __launch_bounds__(256) void gate_rms_k(const ushort_t* __restrict__ Yb,
                                                  const ushort_t* __restrict__ zx,
                                                  const float* __restrict__ rms_w,
                                                  ushort_t* __restrict__ yn){
    __shared__ float red[4];
    __shared__ float scale_s;
    int row = blockIdx.x; int tid = threadIdx.x;
    float v[8]; float ss = 0.f;
    #pragma unroll
    for (int i = 0; i < 8; i++){
        int d = tid + i*256;
        float g = b2f(Yb[(size_t)row*DI + d]) * silu_f(b2f(zx[(size_t)row*DPROJ + d]));
        v[i] = g; ss += g*g;
    }
    #pragma unroll
    for (int off = 32; off > 0; off >>= 1) ss += __shfl_down(ss, off);
    int lane = tid & 63, wid = tid >> 6;
    if (lane == 0) red[wid] = ss;
    __syncthreads();
    if (tid == 0) scale_s = rsqrtf((red[0]+red[1]+red[2]+red[3])*(1.f/DI) + 1e-12f);
    __syncthreads();
    float sc = scale_s;
    #pragma unroll
    for (int i = 0; i < 8; i++){
        int d = tid + i*256;
        yn[(size_t)row*DI + d] = f2b(v[i]*sc*rms_w[d]);
    }
}

// -------- LN(a + a2 + resid_f32) -> bf16 only (mid LN)
__global__ __launch_bounds__(256) void ln_hbf_k(const float* __restrict__ a,
                                                const float* __restrict__ a2,
                                                const float* __restrict__ resid,
                                                const float* __restrict__ g,
                                                const float* __restrict__ bw,
                                                ushort_t* __restrict__ bfout){
    __shared__ float redA[4], redB[4];
    __shared__ float mu_s, rs_s;
    int row = blockIdx.x; int tid = threadIdx.x;
    float u[4]; float s = 0.f, s2 = 0.f;
    #pragma unroll
    for (int i = 0; i < 4; i++){
        int d = tid + i*256;
        float val = a[(size_t)row*DM + d] + a2[(size_t)row*DM + d] + resid[(size_t)row*DM + d];
        u[i] = val; s += val; s2 += val*val;
    }
    #pragma unroll
    for (int off = 32; off > 0; off >>= 1){
        s  += __shfl_down(s,  off);
        s2 += __shfl_down(s2, off);
    }
    int lane = tid & 63, wid = tid >> 6;
    if (lane == 0){ redA[wid] = s; redB[wid] = s2; }
    __syncthreads();
    if (tid == 0){
        float S  = redA[0]+redA[1]+redA[2]+redA[3];
        float S2 = redB[0]+redB[1]+redB[2]+redB[3];
        float mu = S*(1.f/DM);
        float var = S2*(1.f/DM) - mu*mu;
        mu_s = mu; rs_s = rsqrtf(var + 1e-12f);
    }
    __syncthreads();
    float mu = mu_s, rs = rs_s;
    #pragma unroll
    for (int i = 0; i < 4; i++){
        int d = tid + i*256;
        bfout[(size_t)row*DM + d] = f2b((u[i]-mu)*rs*g[d] + bw[d]);
    }
}

// -------- final LN(a + a2 + resid_bf16) -> fp32 d_out; extra blocks copy td
__global__ __launch_bounds__(256) void ln_final_k(const float* __restrict__ a,
                                                  const float* __restrict__ a2,
                                                  const ushort_t* __restrict__ residb,
                                                  const float* __restrict__ g,
                                                  const float* __restrict__ bw,
                                                  float* __restrict__ outp,
                                                  const float* __restrict__ td){
    __shared__ float redA[4], redB[4];
    __shared__ float mu_s, rs_s;
    int row = blockIdx.x; int tid = threadIdx.x;
    if (row >= ROWS){
        int idx = (row - ROWS)*256 + tid;
        outp[(size_t)ROWS*DM + idx] = td[idx];
        return;
    }
    float u[4]; float s = 0.f, s2 = 0.f;
    #pragma unroll
    for (int i = 0; i < 4; i++){
        int d = tid + i*256;
        float val = a[(size_t)row*DM + d] + a2[(size_t)row*DM + d] + b2f(residb[(size_t)row*DM + d]);
        u[i] = val; s += val; s2 += val*val;
    }
    #pragma unroll
    for (int off = 32; off > 0; off >>= 1){
        s  += __shfl_down(s,  off);
        s2 += __shfl_down(s2, off);
    }
    int lane = tid & 63, wid = tid >> 6;
    if (lane == 0){ redA[wid] = s; redB[wid] = s2; }
    __syncthreads();
    if (tid == 0){
        float S  = redA[0]+redA[1]+redA[2]+redA[3];
        float S2 = redB[0]+redB[1]+redB[2]+redB[3];
        float mu = S*(1.f/DM);
        float var = S2*(1.f/DM) - mu*mu;
        mu_s = mu; rs_s = rsqrtf(var + 1e-12f);
    }
    __syncthreads();
    float mu = mu_s, rs = rs_s;
    #pragma unroll
    for (int i = 0; i < 4; i++){
        int d = tid + i*256;
        outp[(size_t)row*DM + d] = (u[i]-mu)*rs*g[d] + bw[d];
    }
}

extern "C" void kernel_launch(void* const* d_in, const int* in_sizes, int n_in,
                              void* d_out, int out_size, void* d_ws, size_t ws_size,
                              hipStream_t stream){
    const float* x         = (const float*)d_in[0];
    const float* time_diff = (const float*)d_in[1];
    const float* W_in      = (const float*)d_in[2];
    const float* b_in      = (const float*)d_in[3];
    const float* conv_w    = (const float*)d_in[4];
    const float* conv_b    = (const float*)d_in[5];
    const float* A_log     = (const float*)d_in[6];
    const float* dt_bias   = (const float*)d_in[7];
    const float* Dp        = (const float*)d_in[8];
    const float* time_dec  = (const float*)d_in[9];
    const float* rms_w     = (const float*)d_in[10];
    const float* W_out     = (const float*)d_in[11];
    const float* b_out     = (const float*)d_in[12];
    const float* ln_g      = (const float*)d_in[13];
    const float* ln_b      = (const float*)d_in[14];
    const float* fc1_w     = (const float*)d_in[15];
    const float* fc1_b     = (const float*)d_in[16];
    const float* fc2_w     = (const float*)d_in[17];
    const float* fc2_b     = (const float*)d_in[18];
    const float* ln2_g     = (const float*)d_in[19];
    const float* ln2_b     = (const float*)d_in[20];

    float* ws = (float*)d_ws;
    float* zx    = ws;                       // region1: 17,956,864 f
    float* convb = zx    + 17956864;         // region2:  9,437,184 f
    float* dtH   = convb + 9437184;
    float* Acum  = dtH   + 131072;
    float* r4    = Acum  + 131072;           // region4:  8,388,608 f
    float* r5    = r4    + 8388608;          // region5:  9,437,184 f
    float* ybreg = r5    + 9437184;          // region6:  4,194,304 f
    // region1 aliases
    ushort_t* zx_bf  = (ushort_t*)zx;                 // steps 2-8
    float*    dtaux  = zx + 10600000;                 // steps 2-3
    ushort_t* mid_bf = (ushort_t*)zx;                 // steps 12-13 (zx dead)
    ushort_t* h_bf   = (ushort_t*)(zx + 8388608);     // steps 11-14 (zx dead)
    // region2 aliases
    ushort_t* convb_bf = (ushort_t*)convb;            // steps 3-7
    float* outPa  = convb;                            // steps 10-11 (convb dead)
    // region4 aliases
    ushort_t* x_bf  = (ushort_t*)r4;                  // steps 1-2
    ushort_t* WinT  = (ushort_t*)(r4 + 2097152);      // steps 1-2 (4608x1024 bf16)
    ushort_t* WoutT = (ushort_t*)(r4 + 4194304);      // steps 9-10
    float* fc2Pa = r4;                                // steps 13-14
    // region5 aliases
    ushort_t* Gb   = (ushort_t*)r5;                   // steps 4-7
    float* stat = r5 + 1048576;                       // steps 5-6
    float* prev = stat + 4194304;                     // steps 6-7
    ushort_t* yn_bf = (ushort_t*)r5;                  // steps 8-10 (G/stat dead)
    ushort_t* fc1T  = (ushort_t*)(r5 + 4194304);      // steps 9-12 (stat/prev dead)
    ushort_t* fc2T  = (ushort_t*)(r5 + 6291456);      // steps 9-13 (prev dead)
    // region6
    ushort_t* Ybf = (ushort_t*)ybreg;                 // steps 7-8
    float* outp   = (float*)d_out;

    // 1. f2b(x) + W_in^T (merged; W_in^T zero-padded to 4608 rows)
    prep_in_k<<<16384 + 4608, 256, 0, stream>>>(x, x_bf, W_in, WinT);
    // 2a. in-proj cols 0..4095: 256x256 8-phase, grid 16x16 = 256 blocks
    //     (exactly one residency round at 1 block/CU — the kernel's sweet spot)
    gemm256_k<0><<<256, 512, 0, stream>>>(x_bf, WinT, b_in, zx_bf,
                                          ROWS, 4096, DM, DPROJ, 16);
    // 2b. in-proj cols 4096..4383 (N=288, incl. 32 dt cols -> fp32 sidecar):
    //     legacy kernel, 3x32 = 96 blocks (runs at <0.5 blocks/CU, ~8-10 us).
    //     B-rows 4384..4479 overread hits WinT's zero padding.
    mfma_gemm_k<0,1,128,1,1><<<dim3(3, ROWS/128), 256, 0, stream>>>(
        x_bf, WinT + (size_t)4096*DM, b_in + 4096, nullptr,
        zx_bf + 4096, dtaux, ROWS, 288, DM, DPROJ);
    // 3. conv+SiLU -> bf16 convb, merged with dt/dA/cumsum scan
    conv_dt_k<<<CONVBLKS + BATCH*NHEADS*NC, 256, 0, stream>>>(zx_bf, conv_w, conv_b, convb_bf,
                                                              dtaux, time_diff, A_log, dt_bias, time_dec, dtH, Acum);
    // 4. G = C @ B^T (MFMA, bf16)
    g_mfma_k<<<dim3(4,4,BATCH*NC), 256, 0, stream>>>(convb_bf, Gb);
    // 5. per-chunk states (MFMA, xdt derived in staging)
    states_mfma_k<<<BATCH*NC*NHEADS, 256, 0, stream>>>(convb_bf, dtH, Acum, stat);
    // 6. inter-chunk scan (1024 blocks)
    prev_scan_k<<<BATCH*NHEADS*16, 256, 0, stream>>>(stat, Acum, prev);
    // 7. MFMA SSD output -> bf16 Y
    y_mfma_k<<<BATCH*NC*NHEADS, 256, 0, stream>>>(convb_bf, Gb, Acum, dtH, prev, Dp, Ybf);
    // 8. gate + RMSNorm -> bf16 yn
    gate_rms_k<<<ROWS, 256, 0, stream>>>(Ybf, zx_bf, rms_w, yn_bf);
    // 9. W_out / fc1 / fc2 transposes (merged)
    transpose3_k<<<10240, 256, 0, stream>>>(W_out, fc1_w, fc2_w, WoutT, fc1T, fc2T);
    // 10. out-proj split-K=2 (M=4096,N=1024,K=2048): legacy (4+ blocks/CU
    //     overlaps fp32 epilogue across blocks — measured faster than 8-phase split-K)
    mfma_gemm_k<0,0,64,2,0><<<dim3(DM/64, ROWS/128, 2), 256, 0, stream>>>(yn_bf, WoutT, b_out, outPa, nullptr, nullptr, ROWS, DM, DI, DM);
    // 11. h = LN(Pa + Pb + x) -> bf16 only
    ln_hbf_k<<<ROWS, 256, 0, stream>>>(outPa, outPa + (size_t)ROWS*DM, x, ln_g, ln_b, h_bf);
    // 12. fc1 + hardswish -> bf16 mid (M=4096,N=4096,K=1024), 8-phase, grid 256
    gemm256_k<1><<<256, 512, 0, stream>>>(h_bf, fc1T, fc1_b, mid_bf,
                                          ROWS, DFF, DM, DFF, 16);
    // 13. fc2 split-K=2 (M=4096,N=1024,K=4096): legacy
    mfma_gemm_k<0,0,64,2,0><<<dim3(DM/64, ROWS/128, 2), 256, 0, stream>>>(mid_bf, fc2T, fc2_b, fc2Pa, nullptr, nullptr, ROWS, DM, DFF, DM);
    // 14. out = LN(Pa + Pb + h_bf) + td passthrough (merged)
    ln_final_k<<<ROWS + ROWS/256, 256, 0, stream>>>(fc2Pa, fc2Pa + (size_t)ROWS*DM, h_bf, ln2_g, ln2_b, outp, time_diff);
}

// Round 5
// 462.177 us; speedup vs baseline: 1.1228x; 1.1228x over previous
//
#include <hip/hip_runtime.h>

#define BATCH 2
#define SEQL 2048
#define DM 1024
#define DSTATE 128
#define HD 64
#define CHUNK 256
#define DI 2048
#define NHEADS 32
#define CONVD 2304
#define DPROJ 4384
#define DPROJ_PAD 4608
#define DFF 4096
#define NC 8
#define ROWS (BATCH*SEQL)

typedef unsigned short ushort_t;
typedef short bf16x8 __attribute__((ext_vector_type(8)));
typedef short bf16x4 __attribute__((ext_vector_type(4)));
typedef float f32x4 __attribute__((ext_vector_type(4)));

__device__ __forceinline__ float softplus_f(float v){
    return (v > 20.f) ? v : log1pf(expf(v));
}
__device__ __forceinline__ float silu_f(float v){
    return v / (1.f + expf(-v));
}
__device__ __forceinline__ ushort_t f2b(float v){
    union { float f; unsigned int u; } x; x.f = v;
    unsigned int r = x.u + 0x7fffu + ((x.u >> 16) & 1u);
    return (ushort_t)(r >> 16);
}
__device__ __forceinline__ float b2f(ushort_t v){
    union { unsigned int u; float f; } x; x.u = ((unsigned int)v) << 16;
    return x.f;
}

// ================================================================ MFMA GEMM (legacy 128-row tile)
// C[M,N] = A[M,K](bf16) @ Bt[N,K](bf16)^T + bias. BM=128, BN=TN, BK=64.
// 32 KiB LDS -> 4-5 blocks/CU (inter-block overlap hides staging/epilogue).
// Measured best for K=1024..4096 shapes in this net (573-593 TF).
// XCD-aware bijective swizzle on (bx,by) — requires gridDim.x*gridDim.y % 8 == 0.
template<int ACT, int OUT_BF16, int TN, int NS, int DTX>
__global__ __launch_bounds__(256) void mfma_gemm_k(
    const ushort_t* __restrict__ A, const ushort_t* __restrict__ Bt,
    const float* __restrict__ bias, float* __restrict__ Cf,
    ushort_t* __restrict__ Cb, float* __restrict__ dtaux,
    int M, int N, int K, int ldc)
{
    constexpr int NT = (TN == 128) ? 4 : 2;
    constexpr int BROWS = TN / 4;
    __shared__ ushort_t As[128*64];
    __shared__ ushort_t Bs[TN*64];
    int tid = threadIdx.x;
    int lane = tid & 63, wave = tid >> 6;
    // XCD swizzle over linearized (x,y): each XCD gets a contiguous id' chunk
    int gx = gridDim.x;
    int nb = gx * gridDim.y;
    int id = blockIdx.x + gx * blockIdx.y;
    int ids = ((nb & 7) == 0) ? ((id & 7) * (nb >> 3) + (id >> 3)) : id;
    int m0 = (ids / gx) * 128, n0 = (ids % gx) * TN;
    int Ks = K / NS;
    int kb = (NS > 1) ? blockIdx.z * Ks : 0;
    int wave_m = (TN==128) ? (wave >> 1)*64 : (wave & 1)*64;
    int wave_n = (TN==128) ? (wave & 1)*64 : (wave >> 1)*32;
    int lrow = lane >> 3;
    int lcol = ((lane & 7) ^ lrow) * 8;
    const ushort_t* Abase = A  + (size_t)(m0 + wave*32    + lrow)*K + lcol + kb;
    const ushort_t* Bbase = Bt + (size_t)(n0 + wave*BROWS + lrow)*K + lcol + kb;
    ushort_t* AsW = &As[(wave*32)*64];
    ushort_t* BsW = &Bs[(wave*BROWS)*64];
    f32x4 acc[4][NT];
    #pragma unroll
    for (int i=0;i<4;i++)
        #pragma unroll
        for (int j=0;j<NT;j++) acc[i][j] = (f32x4){0.f,0.f,0.f,0.f};
    int lm = lane & 15;
    int quad = lane >> 4;
    for (int k0 = 0; k0 < Ks; k0 += 64){
        #pragma unroll
        for (int j = 0; j < 4; j++)
            __builtin_amdgcn_global_load_lds(
                (const __attribute__((address_space(1))) void*)(Abase + (size_t)(j*8)*K + k0),
                (__attribute__((address_space(3))) void*)(AsW + j*8*64), 16, 0, 0);
        #pragma unroll
        for (int j = 0; j < BROWS/8; j++)
            __builtin_amdgcn_global_load_lds(
                (const __attribute__((address_space(1))) void*)(Bbase + (size_t)(j*8)*K + k0),
                (__attribute__((address_space(3))) void*)(BsW + j*8*64), 16, 0, 0);
        __syncthreads();
        #pragma unroll
        for (int kk = 0; kk < 64; kk += 32){
            int cb = kk >> 3;
            bf16x8 af[4], bfr[NT];
            #pragma unroll
            for (int mt=0; mt<4; mt++)
                af[mt] = *(const bf16x8*)&As[(wave_m + mt*16 + lm)*64 + (((cb + quad) ^ (lm & 7))*8)];
            #pragma unroll
            for (int nt=0; nt<NT; nt++)
                bfr[nt] = *(const bf16x8*)&Bs[(wave_n + nt*16 + lm)*64 + (((cb + quad) ^ (lm & 7))*8)];
            #pragma unroll
            for (int mt=0; mt<4; mt++)
                #pragma unroll
                for (int nt=0; nt<NT; nt++)
                    acc[mt][nt] = __builtin_amdgcn_mfma_f32_16x16x32_bf16(af[mt], bfr[nt], acc[mt][nt], 0, 0, 0);
        }
        __syncthreads();
    }
    float* Cfo = Cf + (size_t)((NS > 1) ? blockIdx.z : 0) * (size_t)M * ldc;
    int addb = (NS == 1) || (blockIdx.z == 0);
    int crow0 = m0 + wave_m + quad * 4;
    int ccol0 = n0 + wave_n + lm;
    #pragma unroll
    for (int mt=0; mt<4; mt++){
        #pragma unroll
        for (int nt=0; nt<NT; nt++){
            int col = ccol0 + nt*16;
            if (col < N){
                float bv = addb ? bias[col] : 0.f;
                #pragma unroll
                for (int r=0; r<4; r++){
                    int row = crow0 + mt*16 + r;
                    float v = acc[mt][nt][r] + bv;
                    if (ACT == 1){
                        float t = fminf(fmaxf(v + 3.f, 0.f), 6.f);
                        v = v * t * (1.f/6.f);
                    }
                    if (OUT_BF16){
                        Cb[(size_t)row*ldc + col] = f2b(v);
                        if (DTX && col >= N - NHEADS)
                            dtaux[(size_t)row*NHEADS + (col - (N - NHEADS))] = v;
                    } else {
                        Cfo[(size_t)row*ldc + col] = v;
                    }
                }
            }
        }
    }
}

// ================================================================ 256x256 8-phase GEMM
// Measured: 61 us for M=4096,N=4096,K=1024 at grid 256 (563 TF) — on par with
// legacy, used only for fc1 (where it was measured). ONLY launch with grid==256.
template<int ACT>
__global__ __launch_bounds__(512) void gemm256_k(
    const ushort_t* __restrict__ A, const ushort_t* __restrict__ Bt,
    const float* __restrict__ bias, ushort_t* __restrict__ Cb,
    int M, int N, int K, int ldc, int nbx)
{
    __shared__ ushort_t sm[65536];          // 128 KiB
    const int tid  = threadIdx.x;
    const int lane = tid & 63, wave = tid >> 6;
    const int lm   = lane & 15, quad = lane >> 4;
    const int wm   = wave >> 2, wn = wave & 3;
    const int nwg = gridDim.x;
    const int cpx = nwg >> 3;
    const int swz = (blockIdx.x & 7)*cpx + (blockIdx.x >> 3);
    const int bx = swz % nbx, by = swz / nbx;
    const int m0 = by << 8, n0 = bx << 8;
    const int NT  = K >> 6;
    const int srow = tid >> 2;
    const int scol = (((tid & 3) ^ ((srow >> 1) & 3)) << 3);
    const ushort_t* pA = A  + (size_t)(m0 + srow)*K + scol;
    const ushort_t* pB = Bt + (size_t)(n0 + srow)*K + scol;
    const size_t rstep = (size_t)128 * K;
    const int swz8 = ((quad ^ ((lm >> 1) & 3)) << 3);
    const int aoff = (wm*128 + lm)*32 + swz8;
    const int boff = 16384 + (wn*64 + lm)*32 + swz8;

#define GL(off, src) __builtin_amdgcn_global_load_lds( \
        (const __attribute__((address_space(1))) void*)(src), \
        (__attribute__((address_space(3))) void*)(&sm[off]), 16, 0, 0)

    {
        const int d = wave*512;
        GL(d,                 pA);        GL(d + 4096,          pA + rstep);
        GL(d + 16384,         pB);        GL(d + 16384 + 4096,  pB + rstep);
        GL(d + 8192,          pA + 32);   GL(d + 8192 + 4096,   pA + 32 + rstep);
        GL(d + 24576,         pB + 32);   GL(d + 24576 + 4096,  pB + 32 + rstep);
    }
    asm volatile("s_waitcnt vmcnt(0)" ::: "memory");
    __builtin_amdgcn_sched_barrier(0);
    __builtin_amdgcn_s_barrier();

    f32x4 acc[8][4];
    #pragma unroll
    for (int i = 0; i < 8; i++)
        #pragma unroll
        for (int j = 0; j < 4; j++) acc[i][j] = (f32x4){0.f,0.f,0.f,0.f};

#define MFMA16(MH) \
    __builtin_amdgcn_s_setprio(1); \
    _Pragma("unroll") \
    for (int mt = 0; mt < 4; mt++) \
        _Pragma("unroll") \
        for (int nt = 0; nt < 4; nt++) \
            acc[(MH)*4+mt][nt] = __builtin_amdgcn_mfma_f32_16x16x32_bf16(af[mt], bf[nt], acc[(MH)*4+mt][nt], 0, 0, 0); \
    __builtin_amdgcn_s_setprio(0);

    for (int t = 0; t < NT; ++t){
        const int bo = (t & 1) << 15;
        const int nb = bo ^ 32768;
        const bool stg = (t < NT-1);
        const ushort_t* pAn = pA + (size_t)(t+1)*64;
        const ushort_t* pBn = pB + (size_t)(t+1)*64;
        bf16x8 af[4], bf[4];

        #pragma unroll
        for (int nt = 0; nt < 4; nt++) bf[nt] = *(const bf16x8*)&sm[bo + boff + nt*512];
        #pragma unroll
        for (int mt = 0; mt < 4; mt++) af[mt] = *(const bf16x8*)&sm[bo + aoff + mt*512];
        if (stg){ GL(nb + wave*512, pAn); GL(nb + 4096 + wave*512, pAn + rstep); }
        __builtin_amdgcn_s_barrier();
        asm volatile("s_waitcnt lgkmcnt(0)");
        __builtin_amdgcn_sched_barrier(0);
        MFMA16(0)
        __builtin_amdgcn_s_barrier();

        #pragma unroll
        for (int mt = 0; mt < 4; mt++) af[mt] = *(const bf16x8*)&sm[bo + aoff + 2048 + mt*512];
        if (stg){ GL(nb + 16384 + wave*512, pBn); GL(nb + 16384 + 4096 + wave*512, pBn + rstep); }
        if (stg) asm volatile("s_waitcnt vmcnt(4)" ::: "memory");
        else     asm volatile("s_waitcnt vmcnt(0)" ::: "memory");
        __builtin_amdgcn_sched_barrier(0);
        __builtin_amdgcn_s_barrier();
        asm volatile("s_waitcnt lgkmcnt(0)");
        __builtin_amdgcn_sched_barrier(0);
        MFMA16(1)
        __builtin_amdgcn_s_barrier();

        #pragma unroll
        for (int nt = 0; nt < 4; nt++) bf[nt] = *(const bf16x8*)&sm[bo + 8192 + boff + nt*512];
        #pragma unroll
        for (int mt = 0; mt < 4; mt++) af[mt] = *(const bf16x8*)&sm[bo + 8192 + aoff + 2048 + mt*512];
        if (stg){ GL(nb + 8192 + wave*512, pAn + 32); GL(nb + 8192 + 4096 + wave*512, pAn + 32 + rstep); }
        __builtin_amdgcn_s_barrier();
        asm volatile("s_waitcnt lgkmcnt(0)");
        __builtin_amdgcn_sched_barrier(0);
        MFMA16(1)
        __builtin_amdgcn_s_barrier();

        #pragma unroll
        for (int mt = 0; mt < 4; mt++) af[mt] = *(const bf16x8*)&sm[bo + 8192 + aoff + mt*512];
        if (stg){
            GL(nb + 24576 + wave*512, pBn + 32); GL(nb + 24576 + 4096 + wave*512, pBn + 32 + rstep);
            asm volatile("s_waitcnt vmcnt(4)" ::: "memory");
            __builtin_amdgcn_sched_barrier(0);
        }
        __builtin_amdgcn_s_barrier();
        asm volatile("s_waitcnt lgkmcnt(0)");
        __builtin_amdgcn_sched_barrier(0);
        MFMA16(0)
        __builtin_amdgcn_s_barrier();
    }
#undef MFMA16
#undef GL

    const int crow = m0 + wm*128 + quad*4;
    const int ccol = n0 + wn*64 + lm;
    #pragma unroll
    for (int m8 = 0; m8 < 8; m8++){
        #pragma unroll
        for (int nt = 0; nt < 4; nt++){
            int col = ccol + nt*16;
            float bv = bias[col];
            #pragma unroll
            for (int r = 0; r < 4; r++){
                int row = crow + m8*16 + r;
                float v = acc[m8][nt][r] + bv;
                if (ACT == 1){
                    float tt = fminf(fmaxf(v + 3.f, 0.f), 6.f);
                    v = v * tt * (1.f/6.f);
                }
                Cb[(size_t)row*ldc + col] = f2b(v);
            }
        }
    }
}

// ---------------- merged: f2b(x) float4-vectorized [blocks 0..4095] + W_in transpose
// W_in^T padded to DPROJ_PAD=4608 rows (zeros past DPROJ) so the in-proj GEMM
// at grid x=35 can overread B rows 4384..4479 safely.
__global__ __launch_bounds__(256) void prep_in_k(const float* __restrict__ x,
                                                 ushort_t* __restrict__ x_bf,
                                                 const float* __restrict__ W_in,
                                                 ushort_t* __restrict__ WinT){
    __shared__ ushort_t tile[32][33];
    int bid = blockIdx.x;
    if (bid < 4096){
        int idx = (bid*256 + threadIdx.x)*4;
        float4 v = *(const float4*)&x[idx];
        bf16x4 o;
        o[0] = (short)f2b(v.x); o[1] = (short)f2b(v.y);
        o[2] = (short)f2b(v.z); o[3] = (short)f2b(v.w);
        *(bf16x4*)&x_bf[idx] = o;
        return;
    }
    int id2 = bid - 4096;                   // 4608 transpose blocks (144 x 32)
    int n0 = (id2 % 144)*32, k0 = (id2 / 144)*32;
    int tx = threadIdx.x & 31, ty = threadIdx.x >> 5;
    #pragma unroll
    for (int i = 0; i < 4; i++){
        int k = k0 + ty + i*8;
        int n = n0 + tx;
        float v = (n < DPROJ) ? W_in[(size_t)k*DPROJ + n] : 0.f;
        tile[ty + i*8][tx] = f2b(v);
    }
    __syncthreads();
    #pragma unroll
    for (int i = 0; i < 4; i++)
        WinT[(size_t)(n0 + ty + i*8)*DM + k0 + tx] = tile[tx][ty + i*8];
}

// ---------------- merged: W_out / fc1 / fc2 transposes in one launch
__global__ __launch_bounds__(256) void transpose3_k(const float* __restrict__ Wout,
                                                    const float* __restrict__ fc1w,
                                                    const float* __restrict__ fc2w,
                                                    ushort_t* __restrict__ WoutT,
                                                    ushort_t* __restrict__ fc1T,
                                                    ushort_t* __restrict__ fc2T){
    __shared__ ushort_t tile[32][33];
    int bid = blockIdx.x;
    const float* W; ushort_t* Wt; int K, N, gx, id;
    if (bid < 2048){        W = Wout; Wt = WoutT; K = DI;  N = DM;  gx = 32;  id = bid; }
    else if (bid < 6144){   W = fc1w; Wt = fc1T;  K = DM;  N = DFF; gx = 128; id = bid - 2048; }
    else {                  W = fc2w; Wt = fc2T;  K = DFF; N = DM;  gx = 32;  id = bid - 6144; }
    int n0 = (id % gx)*32, k0 = (id / gx)*32;
    int tx = threadIdx.x & 31, ty = threadIdx.x >> 5;
    #pragma unroll
    for (int i = 0; i < 4; i++){
        int k = k0 + ty + i*8;
        int n = n0 + tx;
        tile[ty + i*8][tx] = f2b(W[(size_t)k*N + n]);
    }
    __syncthreads();
    #pragma unroll
    for (int i = 0; i < 4; i++)
        Wt[(size_t)(n0 + ty + i*8)*K + k0 + tx] = tile[tx][ty + i*8];
}

// ---- merged: [0, 4608) depthwise conv+SiLU (x8 vectorized); [4608, +512) dt-scan
#define CONVBLKS8 (ROWS*CONVD/(256*8))
__global__ __launch_bounds__(256) void conv_dt_k(const ushort_t* __restrict__ zx,
                                                 const float* __restrict__ conv_w,
                                                 const float* __restrict__ conv_b,
                                                 ushort_t* __restrict__ convb,
                                                 const float* __restrict__ dtaux,
                                                 const float* __restrict__ time_diff,
                                                 const float* __restrict__ A_log,
                                                 const float* __restrict__ dt_bias,
                                                 const float* __restrict__ time_decay,
                                                 float* __restrict__ dtH,
                                                 float* __restrict__ Acum){
    __shared__ float s[CHUNK];
    int bid = blockIdx.x;
    if (bid < CONVBLKS8){
        int idx = (bid*256 + threadIdx.x)*8;
        int c = idx % CONVD;                 // CONVD % 8 == 0 -> c..c+7 same row
        int row = idx / CONVD;
        int t = row & (SEQL-1);
        bf16x8 vk[4];
        bool ok[4];
        #pragma unroll
        for (int k = 0; k < 4; k++){
            int tt = t + k - 3;
            ok[k] = (tt >= 0);
            if (ok[k])
                vk[k] = *(const bf16x8*)&zx[((size_t)(row + k - 3))*DPROJ + DI + c];
        }
        const float4* cw = (const float4*)&conv_w[c*4];
        bf16x8 o;
        #pragma unroll
        for (int j = 0; j < 8; j++){
            float a = conv_b[c + j];
            float4 w = cw[j];
            if (ok[0]) a += b2f((ushort_t)vk[0][j]) * w.x;
            if (ok[1]) a += b2f((ushort_t)vk[1][j]) * w.y;
            if (ok[2]) a += b2f((ushort_t)vk[2][j]) * w.z;
            if (ok[3]) a += b2f((ushort_t)vk[3][j]) * w.w;
            o[j] = (short)f2b(silu_f(a));
        }
        *(bf16x8*)&convb[idx] = o;
        return;
    }
    int id2 = bid - CONVBLKS8;                 // 512 dt blocks
    int c = id2 % NC;
    int h = (id2 / NC) % NHEADS;
    int b = id2 / (NC*NHEADS);
    int l = threadIdx.x;
    int t = c*CHUNK + l;
    float dtr = dtaux[((size_t)(b*SEQL + t))*NHEADS + h];
    float dtv = softplus_f(dtr + dt_bias[h]);
    float A = -expf(A_log[h]);
    float dA = dtv*A - softplus_f(time_decay[h]) * time_diff[b*SEQL + t];
    dtH[((size_t)(b*NHEADS + h))*SEQL + t] = dtv;        // [h][row] layout
    s[l] = dA;
    __syncthreads();
    for (int off = 1; off < CHUNK; off <<= 1){
        float v = (l >= off) ? s[l-off] : 0.f;
        __syncthreads();
        s[l] += v;
        __syncthreads();
    }
    Acum[((size_t)(b*NHEADS + h))*SEQL + t] = s[l];
}

// -------------------- MFMA G[b,c,l,s] = C_l . B_s (64x64x128), bf16 in/out
__global__ __launch_bounds__(256) void g_mfma_k(const ushort_t* __restrict__ convb,
                                                ushort_t* __restrict__ G){
    __shared__ ushort_t As[64*136];
    __shared__ ushort_t Bs[64*136];
    int bc = blockIdx.z;
    int l0 = blockIdx.y*64, s0 = blockIdx.x*64;
    int tid = threadIdx.x;
    int lane = tid & 63, wave = tid >> 6;
    int lm = lane & 15, quad = lane >> 4;
    const ushort_t* base = convb + (size_t)bc*CHUNK*CONVD;
    #pragma unroll
    for (int i = 0; i < 4; i++){
        int e = tid + i*256;
        int r = e >> 4, k = (e & 15)*8;
        *(bf16x8*)&As[r*136 + k] = *(const bf16x8*)&base[(size_t)(l0+r)*CONVD + DI + DSTATE + k];
        *(bf16x8*)&Bs[r*136 + k] = *(const bf16x8*)&base[(size_t)(s0+r)*CONVD + DI + k];
    }
    __syncthreads();
    f32x4 acc[4];
    #pragma unroll
    for (int j=0;j<4;j++) acc[j] = (f32x4){0.f,0.f,0.f,0.f};
    #pragma unroll
    for (int kk = 0; kk < 4; kk++){
        bf16x8 af = *(const bf16x8*)&As[(wave*16+lm)*136 + kk*32 + quad*8];
        #pragma unroll
        for (int nt = 0; nt < 4; nt++){
            bf16x8 bfr = *(const bf16x8*)&Bs[(nt*16+lm)*136 + kk*32 + quad*8];
            acc[nt] = __builtin_amdgcn_mfma_f32_16x16x32_bf16(af, bfr, acc[nt], 0, 0, 0);
        }
    }
    ushort_t* g = G + (size_t)bc*CHUNK*CHUNK;
    #pragma unroll
    for (int nt = 0; nt < 4; nt++)
        #pragma unroll
        for (int r = 0; r < 4; r++)
            g[(size_t)(l0 + wave*16 + quad*4 + r)*CHUNK + s0 + nt*16 + lm] = f2b(acc[nt][r]);
}

// ---- MFMA states[b,c,h,p,n] = sum_l B[l,n]*exp(AcL-Ac[l])*dt[l]*xs[l,p]
#define RSX 264
#define RSB 72
__global__ __launch_bounds__(256) void states_mfma_k(const ushort_t* __restrict__ convb,
                                                     const float* __restrict__ dtH,
                                                     const float* __restrict__ Acum,
                                                     float* __restrict__ states){
    __shared__ ushort_t xw[64*RSX];
    __shared__ ushort_t Bt[128*RSB];
    __shared__ float Acs[CHUNK];
    __shared__ float esc[CHUNK];
    int bid = blockIdx.x;
    int h = bid % NHEADS;
    int c = (bid / NHEADS) % NC;
    int b = bid / (NHEADS*NC);
    int tid = threadIdx.x;
    int lane = tid & 63, wave = tid >> 6;
    int lm = lane & 15, quad = lane >> 4;
    Acs[tid] = Acum[((size_t)(b*NHEADS + h))*SEQL + c*CHUNK + tid];
    float dtv = dtH[((size_t)(b*NHEADS + h))*SEQL + c*CHUNK + tid];
    __syncthreads();
    // esc[l] = exp(AcL - Ac[l]) * dt[l], computed ONCE per row (was 64x/lane)
    esc[tid] = expf(Acs[CHUNK-1] - Acs[tid]) * dtv;
    __syncthreads();
    {
        const ushort_t* xg = convb + ((size_t)(b*SEQL + c*CHUNK))*CONVD + h*HD;
        #pragma unroll
        for (int j8 = 0; j8 < 8; j8++){
            int s0 = wave*64 + j8*8;
            bf16x8 pk;
            #pragma unroll
            for (int j = 0; j < 8; j++){
                int l = s0 + j;
                pk[j] = (short)f2b(esc[l] * b2f(xg[(size_t)l*CONVD + lane]));
            }
            *(bf16x8*)&xw[lane*RSX + s0] = pk;
        }
    }
    f32x4 acc[8];
    #pragma unroll
    for (int j=0;j<8;j++) acc[j] = (f32x4){0.f,0.f,0.f,0.f};
    const ushort_t* bbase = convb + ((size_t)(b*SEQL + c*CHUNK))*CONVD + DI;
    for (int l0 = 0; l0 < CHUNK; l0 += 64){
        __syncthreads();
        #pragma unroll
        for (int i = 0; i < 32; i++){
            int e = tid + i*256; int l = e >> 7, n = e & 127;
            Bt[n*RSB + l] = bbase[(size_t)(l0+l)*CONVD + n];
        }
        __syncthreads();
        #pragma unroll
        for (int kk = 0; kk < 2; kk++){
            bf16x8 af = *(const bf16x8*)&xw[(wave*16+lm)*RSX + l0 + kk*32 + quad*8];
            #pragma unroll
            for (int nt = 0; nt < 8; nt++){
                bf16x8 bfr = *(const bf16x8*)&Bt[(nt*16+lm)*RSB + kk*32 + quad*8];
                acc[nt] = __builtin_amdgcn_mfma_f32_16x16x32_bf16(af, bfr, acc[nt], 0, 0, 0);
            }
        }
    }
    float* outp = states + ((size_t)((b*NC + c)*NHEADS + h))*(HD*DSTATE);
    #pragma unroll
    for (int nt = 0; nt < 8; nt++)
        #pragma unroll
        for (int r = 0; r < 4; r++)
            outp[(size_t)(wave*16 + quad*4 + r)*DSTATE + nt*16 + lm] = acc[nt][r];
}

// ------------- inter-chunk recurrence, 16-way split over (p,n) elements
__global__ __launch_bounds__(256) void prev_scan_k(const float* __restrict__ states,
                                                   const float* __restrict__ Acum,
                                                   float* __restrict__ prev){
    int bid = blockIdx.x;                  // B*NHEADS*16
    int part = bid & 15;
    int h = (bid >> 4) & (NHEADS-1);
    int b = bid >> 9;
    int tid = threadIdx.x;
    const float* AcB = Acum + ((size_t)(b*NHEADS + h))*SEQL;
    float dec[NC];
    #pragma unroll
    for (int c = 0; c < NC; c++) dec[c] = expf(AcB[c*CHUNK + CHUNK-1]);
    #pragma unroll
    for (int j = 0; j < 2; j++){
        int e = part*512 + j*256 + tid;
        float carry = 0.f;
        #pragma unroll
        for (int c = 0; c < NC; c++){
            size_t idx = ((size_t)((b*NC + c)*NHEADS + h))*(HD*DSTATE) + e;
            prev[idx] = carry;
            carry = carry*dec[c] + states[idx];
        }
    }
}

// ===== MFMA SSD output: Y = P@(dt*xs) + (e^A C)@prev^T + D*xs  -> bf16 Ybf
#define RLX 264
#define RLP 136
__global__ __launch_bounds__(256) void y_mfma_k(const ushort_t* __restrict__ convb,
                                                const ushort_t* __restrict__ G,
                                                const float* __restrict__ Acum,
                                                const float* __restrict__ dtH,
                                                const float* __restrict__ prev,
                                                const float* __restrict__ Dp,
                                                ushort_t* __restrict__ Ybf){
    __shared__ ushort_t xdtT[64*RLX];
    __shared__ ushort_t prevs[64*RLP];
    __shared__ float Acs[CHUNK];
    __shared__ float dts[CHUNK];
    int bid = blockIdx.x;
    int h = bid % NHEADS;
    int c = (bid / NHEADS) % NC;
    int b = bid / (NHEADS*NC);
    int tid = threadIdx.x;
    int lane = tid & 63, wave = tid >> 6;
    int lm = lane & 15, quad = lane >> 4;

    Acs[tid] = Acum[((size_t)(b*NHEADS + h))*SEQL + c*CHUNK + tid];
    dts[tid] = dtH[((size_t)(b*NHEADS + h))*SEQL + c*CHUNK + tid];
    {
        const float* pv = prev + ((size_t)((b*NC + c)*NHEADS + h))*(HD*DSTATE);
        #pragma unroll
        for (int i = 0; i < 32; i++){
            int e = tid + i*256; int p = e >> 7, n = e & 127;
            prevs[p*RLP + n] = f2b(pv[e]);
        }
    }
    __syncthreads();
    {
        const ushort_t* xg = convb + ((size_t)(b*SEQL + c*CHUNK))*CONVD + h*HD;
        #pragma unroll
        for (int j8 = 0; j8 < 8; j8++){
            int s0 = wave*64 + j8*8;
            bf16x8 pk;
            #pragma unroll
            for (int j = 0; j < 8; j++){
                int l = s0 + j;
                pk[j] = (short)f2b(b2f(xg[(size_t)l*CONVD + lane]) * dts[l]);
            }
            *(bf16x8*)&xdtT[lane*RLX + s0] = pk;
        }
    }
    __syncthreads();

    int   lrow[4];  float Alr[4], eAlr[4];
    #pragma unroll
    for (int mt = 0; mt < 4; mt++){
        lrow[mt] = (mt*4 + wave)*16 + lm;
        Alr[mt]  = Acs[lrow[mt]];
        eAlr[mt] = expf(Alr[mt]);
    }
    const ushort_t* Gbase = G + ((size_t)(b*NC + c))*(CHUNK*CHUNK);

    f32x4 acc[4][4];
    #pragma unroll
    for (int i=0;i<4;i++)
        #pragma unroll
        for (int j=0;j<4;j++) acc[i][j] = (f32x4){0.f,0.f,0.f,0.f};

    for (int ks = 0; ks < 8; ks++){
        bf16x8 bfr[4];
        #pragma unroll
        for (int nt = 0; nt < 4; nt++)
            bfr[nt] = *(const bf16x8*)&xdtT[(nt*16+lm)*RLX + ks*32 + quad*8];
        #pragma unroll
        for (int mt = 0; mt < 4; mt++){
            int rblk = mt*4 + wave;
            int nst = rblk/2 + 1;
            if (ks < nst){
                int sbase = ks*32 + quad*8;
                bf16x8 g8 = *(const bf16x8*)&Gbase[(size_t)lrow[mt]*CHUNK + sbase];
                const float4* A4 = (const float4*)(&Acs[sbase]);
                float4 a0 = A4[0], a1 = A4[1];
                float Al = Alr[mt]; int l = lrow[mt];
                float pv[8];
                pv[0] = (sbase+0 <= l) ? b2f((ushort_t)g8[0])*expf(Al - a0.x) : 0.f;
                pv[1] = (sbase+1 <= l) ? b2f((ushort_t)g8[1])*expf(Al - a0.y) : 0.f;
                pv[2] = (sbase+2 <= l) ? b2f((ushort_t)g8[2])*expf(Al - a0.z) : 0.f;
                pv[3] = (sbase+3 <= l) ? b2f((ushort_t)g8[3])*expf(Al - a0.w) : 0.f;
                pv[4] = (sbase+4 <= l) ? b2f((ushort_t)g8[4])*expf(Al - a1.x) : 0.f;
                pv[5] = (sbase+5 <= l) ? b2f((ushort_t)g8[5])*expf(Al - a1.y) : 0.f;
                pv[6] = (sbase+6 <= l) ? b2f((ushort_t)g8[6])*expf(Al - a1.z) : 0.f;
                pv[7] = (sbase+7 <= l) ? b2f((ushort_t)g8[7])*expf(Al - a1.w) : 0.f;
                bf16x8 af;
                #pragma unroll
                for (int j = 0; j < 8; j++) af[j] = (short)f2b(pv[j]);
                #pragma unroll
                for (int nt = 0; nt < 4; nt++)
                    acc[mt][nt] = __builtin_amdgcn_mfma_f32_16x16x32_bf16(af, bfr[nt], acc[mt][nt], 0, 0, 0);
            }
        }
    }
    for (int kc = 0; kc < 4; kc++){
        bf16x8 bfr[4];
        #pragma unroll
        for (int nt = 0; nt < 4; nt++)
            bfr[nt] = *(const bf16x8*)&prevs[(nt*16+lm)*RLP + kc*32 + quad*8];
        #pragma unroll
        for (int mt = 0; mt < 4; mt++){
            int rowg = b*SEQL + c*CHUNK + lrow[mt];
            bf16x8 c8 = *(const bf16x8*)&convb[(size_t)rowg*CONVD + DI + DSTATE + kc*32 + quad*8];
            float e = eAlr[mt];
            bf16x8 af;
            #pragma unroll
            for (int j = 0; j < 8; j++) af[j] = (short)f2b(e * b2f((ushort_t)c8[j]));
            #pragma unroll
            for (int nt = 0; nt < 4; nt++)
                acc[mt][nt] = __builtin_amdgcn_mfma_f32_16x16x32_bf16(af, bfr[nt], acc[mt][nt], 0, 0, 0);
        }
    }
    float Dv = Dp[h];
    #pragma unroll
    for (int mt = 0; mt < 4; mt++){
        int l0 = (mt*4 + wave)*16 + quad*4;
        #pragma unroll
        for (int nt = 0; nt < 4; nt++){
            int p = nt*16 + lm;
            #pragma unroll
            for (int r = 0; r < 4; r++){
                int rowg = b*SEQL + c*CHUNK + l0 + r;
                float xs = b2f(convb[(size_t)rowg*CONVD + h*HD + p]);
                Ybf[(size_t)rowg*DI + h*HD + p] = f2b(acc[mt][nt][r] + Dv*xs);
            }
        }
    }
}

// ------------------------------- y = Y*silu(z); RMSNorm; * rms_w ; -> bf16
__global__ __launch_bounds__(256) void gate_rms_k(const ushort_t* __restrict__ Yb,
                                                  const ushort_t* __restrict__ zx,
                                                  const float* __restrict__ rms_w,
                                                  ushort_t* __restrict__ yn){
    __shared__ float red[4];
    __shared__ float scale_s;
    int row = blockIdx.x; int tid = threadIdx.x;
    float v[8]; float ss = 0.f;
    #pragma unroll
    for (int i = 0; i < 8; i++){
        int d = tid + i*256;
        float g = b2f(Yb[(size_t)row*DI + d]) * silu_f(b2f(zx[(size_t)row*DPROJ + d]));
        v[i] = g; ss += g*g;
    }
    #pragma unroll
    for (int off = 32; off > 0; off >>= 1) ss += __shfl_down(ss, off);
    int lane = tid & 63, wid = tid >> 6;
    if (lane == 0) red[wid] = ss;
    __syncthreads();
    if (tid == 0) scale_s = rsqrtf((red[0]+red[1]+red[2]+red[3])*(1.f/DI) + 1e-12f);
    __syncthreads();
    float sc = scale_s;
    #pragma unroll
    for (int i = 0; i < 8; i++){
        int d = tid + i*256;
        yn[(size_t)row*DI + d] = f2b(v[i]*sc*rms_w[d]);
    }
}

// -------- LN(a + a2 + resid_f32) -> bf16 only (mid LN)
__global__ __launch_bounds__(256) void ln_hbf_k(const float* __restrict__ a,
                                                const float* __restrict__ a2,
                                                const float* __restrict__ resid,
                                                const float* __restrict__ g,
                                                const float* __restrict__ bw,
                                                ushort_t* __restrict__ bfout){
    __shared__ float redA[4], redB[4];
    __shared__ float mu_s, rs_s;
    int row = blockIdx.x; int tid = threadIdx.x;
    float u[4]; float s = 0.f, s2 = 0.f;
    #pragma unroll
    for (int i = 0; i < 4; i++){
        int d = tid + i*256;
        float val = a[(size_t)row*DM + d] + a2[(size_t)row*DM + d] + resid[(size_t)row*DM + d];
        u[i] = val; s += val; s2 += val*val;
    }
    #pragma unroll
    for (int off = 32; off > 0; off >>= 1){
        s  += __shfl_down(s,  off);
        s2 += __shfl_down(s2, off);
    }
    int lane = tid & 63, wid = tid >> 6;
    if (lane == 0){ redA[wid] = s; redB[wid] = s2; }
    __syncthreads();
    if (tid == 0){
        float S  = redA[0]+redA[1]+redA[2]+redA[3];
        float S2 = redB[0]+redB[1]+redB[2]+redB[3];
        float mu = S*(1.f/DM);
        float var = S2*(1.f/DM) - mu*mu;
        mu_s = mu; rs_s = rsqrtf(var + 1e-12f);
    }
    __syncthreads();
    float mu = mu_s, rs = rs_s;
    #pragma unroll
    for (int i = 0; i < 4; i++){
        int d = tid + i*256;
        bfout[(size_t)row*DM + d] = f2b((u[i]-mu)*rs*g[d] + bw[d]);
    }
}

// -------- final LN(a + a2 + resid_bf16) -> fp32 d_out; extra blocks copy td
__global__ __launch_bounds__(256) void ln_final_k(const float* __restrict__ a,
                                                  const float* __restrict__ a2,
                                                  const ushort_t* __restrict__ residb,
                                                  const float* __restrict__ g,
                                                  const float* __restrict__ bw,
                                                  float* __restrict__ outp,
                                                  const float* __restrict__ td){
    __shared__ float redA[4], redB[4];
    __shared__ float mu_s, rs_s;
    int row = blockIdx.x; int tid = threadIdx.x;
    if (row >= ROWS){
        int idx = (row - ROWS)*256 + tid;
        outp[(size_t)ROWS*DM + idx] = td[idx];
        return;
    }
    float u[4]; float s = 0.f, s2 = 0.f;
    #pragma unroll
    for (int i = 0; i < 4; i++){
        int d = tid + i*256;
        float val = a[(size_t)row*DM + d] + a2[(size_t)row*DM + d] + b2f(residb[(size_t)row*DM + d]);
        u[i] = val; s += val; s2 += val*val;
    }
    #pragma unroll
    for (int off = 32; off > 0; off >>= 1){
        s  += __shfl_down(s,  off);
        s2 += __shfl_down(s2, off);
    }
    int lane = tid & 63, wid = tid >> 6;
    if (lane == 0){ redA[wid] = s; redB[wid] = s2; }
    __syncthreads();
    if (tid == 0){
        float S  = redA[0]+redA[1]+redA[2]+redA[3];
        float S2 = redB[0]+redB[1]+redB[2]+redB[3];
        float mu = S*(1.f/DM);
        float var = S2*(1.f/DM) - mu*mu;
        mu_s = mu; rs_s = rsqrtf(var + 1e-12f);
    }
    __syncthreads();
    float mu = mu_s, rs = rs_s;
    #pragma unroll
    for (int i = 0; i < 4; i++){
        int d = tid + i*256;
        outp[(size_t)row*DM + d] = (u[i]-mu)*rs*g[d] + bw[d];
    }
}

extern "C" void kernel_launch(void* const* d_in, const int* in_sizes, int n_in,
                              void* d_out, int out_size, void* d_ws, size_t ws_size,
                              hipStream_t stream){
    const float* x         = (const float*)d_in[0];
    const float* time_diff = (const float*)d_in[1];
    const float* W_in      = (const float*)d_in[2];
    const float* b_in      = (const float*)d_in[3];
    const float* conv_w    = (const float*)d_in[4];
    const float* conv_b    = (const float*)d_in[5];
    const float* A_log     = (const float*)d_in[6];
    const float* dt_bias   = (const float*)d_in[7];
    const float* Dp        = (const float*)d_in[8];
    const float* time_dec  = (const float*)d_in[9];
    const float* rms_w     = (const float*)d_in[10];
    const float* W_out     = (const float*)d_in[11];
    const float* b_out     = (const float*)d_in[12];
    const float* ln_g      = (const float*)d_in[13];
    const float* ln_b      = (const float*)d_in[14];
    const float* fc1_w     = (const float*)d_in[15];
    const float* fc1_b     = (const float*)d_in[16];
    const float* fc2_w     = (const float*)d_in[17];
    const float* fc2_b     = (const float*)d_in[18];
    const float* ln2_g     = (const float*)d_in[19];
    const float* ln2_b     = (const float*)d_in[20];

    float* ws = (float*)d_ws;
    float* zx    = ws;                       // region1: 17,956,864 f
    float* convb = zx    + 17956864;         // region2:  9,437,184 f
    float* dtH   = convb + 9437184;
    float* Acum  = dtH   + 131072;
    float* r4    = Acum  + 131072;           // region4:  8,388,608 f
    float* r5    = r4    + 8388608;          // region5:  9,437,184 f
    float* ybreg = r5    + 9437184;          // region6:  4,194,304 f
    // region1 aliases
    ushort_t* zx_bf  = (ushort_t*)zx;                 // steps 2-8
    float*    dtaux  = zx + 10600000;                 // steps 2-3
    ushort_t* mid_bf = (ushort_t*)zx;                 // steps 12-13 (zx dead)
    ushort_t* h_bf   = (ushort_t*)(zx + 8388608);     // steps 11-14 (zx dead)
    // region2 aliases
    ushort_t* convb_bf = (ushort_t*)convb;            // steps 3-7
    float* outPa  = convb;                            // steps 10-11 (convb dead)
    // region4 aliases
    ushort_t* x_bf  = (ushort_t*)r4;                  // steps 1-2
    ushort_t* WinT  = (ushort_t*)(r4 + 2097152);      // steps 1-2 (4608x1024 bf16)
    ushort_t* WoutT = (ushort_t*)(r4 + 4194304);      // steps 9-10
    float* fc2Pa = r4;                                // steps 13-14
    // region5 aliases
    ushort_t* Gb   = (ushort_t*)r5;                   // steps 4-7
    float* stat = r5 + 1048576;                       // steps 5-6
    float* prev = stat + 4194304;                     // steps 6-7
    ushort_t* yn_bf = (ushort_t*)r5;                  // steps 8-10 (G/stat dead)
    ushort_t* fc1T  = (ushort_t*)(r5 + 4194304);      // steps 9-12 (stat/prev dead)
    ushort_t* fc2T  = (ushort_t*)(r5 + 6291456);      // steps 9-13 (prev dead)
    // region6
    ushort_t* Ybf = (ushort_t*)ybreg;                 // steps 7-8
    float* outp   = (float*)d_out;

    // 1. f2b(x) (float4-vectorized) + W_in^T (zero-padded to 4608 rows)
    prep_in_k<<<4096 + 4608, 256, 0, stream>>>(x, x_bf, W_in, WinT);
    // 2. in-proj (M=4096,N=4384,K=1024): legacy single launch, grid 35x32 = 1120
    //    blocks (4-5/CU), DTX sidecar. Round-0 measured 64.2 us; + XCD swizzle.
    mfma_gemm_k<0,1,128,1,1><<<dim3(35, ROWS/128), 256, 0, stream>>>(
        x_bf, WinT, b_in, nullptr, zx_bf, dtaux, ROWS, DPROJ, DM, DPROJ);
    // 3. conv+SiLU (x8 vectorized) -> bf16 convb, merged with dt/dA/cumsum scan
    conv_dt_k<<<CONVBLKS8 + BATCH*NHEADS*NC, 256, 0, stream>>>(zx_bf, conv_w, conv_b, convb_bf,
                                                               dtaux, time_diff, A_log, dt_bias, time_dec, dtH, Acum);
    // 4. G = C @ B^T (MFMA, bf16)
    g_mfma_k<<<dim3(4,4,BATCH*NC), 256, 0, stream>>>(convb_bf, Gb);
    // 5. per-chunk states (MFMA; esc[] precomputed once per row)
    states_mfma_k<<<BATCH*NC*NHEADS, 256, 0, stream>>>(convb_bf, dtH, Acum, stat);
    // 6. inter-chunk scan (1024 blocks)
    prev_scan_k<<<BATCH*NHEADS*16, 256, 0, stream>>>(stat, Acum, prev);
    // 7. MFMA SSD output -> bf16 Y
    y_mfma_k<<<BATCH*NC*NHEADS, 256, 0, stream>>>(convb_bf, Gb, Acum, dtH, prev, Dp, Ybf);
    // 8. gate + RMSNorm -> bf16 yn
    gate_rms_k<<<ROWS, 256, 0, stream>>>(Ybf, zx_bf, rms_w, yn_bf);
    // 9. W_out / fc1 / fc2 transposes (merged)
    transpose3_k<<<10240, 256, 0, stream>>>(W_out, fc1_w, fc2_w, WoutT, fc1T, fc2T);
    // 10. out-proj split-K=2 (M=4096,N=1024,K=2048): legacy
    mfma_gemm_k<0,0,64,2,0><<<dim3(DM/64, ROWS/128, 2), 256, 0, stream>>>(yn_bf, WoutT, b_out, outPa, nullptr, nullptr, ROWS, DM, DI, DM);
    // 11. h = LN(Pa + Pb + x) -> bf16 only
    ln_hbf_k<<<ROWS, 256, 0, stream>>>(outPa, outPa + (size_t)ROWS*DM, x, ln_g, ln_b, h_bf);
    // 12. fc1 + hardswish -> bf16 mid (M=4096,N=4096,K=1024): 8-phase, grid 256
    gemm256_k<1><<<256, 512, 0, stream>>>(h_bf, fc1T, fc1_b, mid_bf,
                                          ROWS, DFF, DM, DFF, 16);
    // 13. fc2 split-K=2 (M=4096,N=1024,K=4096): legacy
    mfma_gemm_k<0,0,64,2,0><<<dim3(DM/64, ROWS/128, 2), 256, 0, stream>>>(mid_bf, fc2T, fc2_b, fc2Pa, nullptr, nullptr, ROWS, DM, DFF, DM);
    // 14. out = LN(Pa + Pb + h_bf) + td passthrough (merged)
    ln_final_k<<<ROWS + ROWS/256, 256, 0, stream>>>(fc2Pa, fc2Pa + (size_t)ROWS*DM, h_bf, ln2_g, ln2_b, outp, time_diff);
}

// Round 6
// 424.749 us; speedup vs baseline: 1.2217x; 1.0881x over previous
//
#include <hip/hip_runtime.h>

#define BATCH 2
#define SEQL 2048
#define DM 1024
#define DSTATE 128
#define HD 64
#define CHUNK 256
#define DI 2048
#define NHEADS 32
#define CONVD 2304
#define DPROJ 4384
#define DPROJ_PAD 4608
#define DFF 4096
#define NC 8
#define ROWS (BATCH*SEQL)

typedef unsigned short ushort_t;
typedef short bf16x8 __attribute__((ext_vector_type(8)));
typedef short bf16x4 __attribute__((ext_vector_type(4)));
typedef float f32x4 __attribute__((ext_vector_type(4)));

__device__ __forceinline__ float softplus_f(float v){
    return (v > 20.f) ? v : log1pf(expf(v));
}
__device__ __forceinline__ float silu_f(float v){
    return v / (1.f + expf(-v));
}
__device__ __forceinline__ ushort_t f2b(float v){
    union { float f; unsigned int u; } x; x.f = v;
    unsigned int r = x.u + 0x7fffu + ((x.u >> 16) & 1u);
    return (ushort_t)(r >> 16);
}
__device__ __forceinline__ float b2f(ushort_t v){
    union { unsigned int u; float f; } x; x.u = ((unsigned int)v) << 16;
    return x.f;
}

// ================================================================ MFMA GEMM (legacy 128-row tile)
// C[M,N] = A[M,K](bf16) @ Bt[N,K](bf16)^T + bias. BM=128, BN=TN, BK=64.
// 32 KiB LDS -> 4-5 blocks/CU (inter-block overlap hides staging/epilogue).
// Measured best for K=1024..4096 shapes in this net (573-593 TF).
// XCD-aware bijective swizzle on (bx,by) — requires gridDim.x*gridDim.y % 8 == 0.
template<int ACT, int OUT_BF16, int TN, int NS, int DTX>
__global__ __launch_bounds__(256) void mfma_gemm_k(
    const ushort_t* __restrict__ A, const ushort_t* __restrict__ Bt,
    const float* __restrict__ bias, float* __restrict__ Cf,
    ushort_t* __restrict__ Cb, float* __restrict__ dtaux,
    int M, int N, int K, int ldc)
{
    constexpr int NT = (TN == 128) ? 4 : 2;
    constexpr int BROWS = TN / 4;
    __shared__ ushort_t As[128*64];
    __shared__ ushort_t Bs[TN*64];
    int tid = threadIdx.x;
    int lane = tid & 63, wave = tid >> 6;
    // XCD swizzle over linearized (x,y): each XCD gets a contiguous id' chunk
    int gx = gridDim.x;
    int nb = gx * gridDim.y;
    int id = blockIdx.x + gx * blockIdx.y;
    int ids = ((nb & 7) == 0) ? ((id & 7) * (nb >> 3) + (id >> 3)) : id;
    int m0 = (ids / gx) * 128, n0 = (ids % gx) * TN;
    int Ks = K / NS;
    int kb = (NS > 1) ? blockIdx.z * Ks : 0;
    int wave_m = (TN==128) ? (wave >> 1)*64 : (wave & 1)*64;
    int wave_n = (TN==128) ? (wave & 1)*64 : (wave >> 1)*32;
    int lrow = lane >> 3;
    int lcol = ((lane & 7) ^ lrow) * 8;
    const ushort_t* Abase = A  + (size_t)(m0 + wave*32    + lrow)*K + lcol + kb;
    const ushort_t* Bbase = Bt + (size_t)(n0 + wave*BROWS + lrow)*K + lcol + kb;
    ushort_t* AsW = &As[(wave*32)*64];
    ushort_t* BsW = &Bs[(wave*BROWS)*64];
    f32x4 acc[4][NT];
    #pragma unroll
    for (int i=0;i<4;i++)
        #pragma unroll
        for (int j=0;j<NT;j++) acc[i][j] = (f32x4){0.f,0.f,0.f,0.f};
    int lm = lane & 15;
    int quad = lane >> 4;
    for (int k0 = 0; k0 < Ks; k0 += 64){
        #pragma unroll
        for (int j = 0; j < 4; j++)
            __builtin_amdgcn_global_load_lds(
                (const __attribute__((address_space(1))) void*)(Abase + (size_t)(j*8)*K + k0),
                (__attribute__((address_space(3))) void*)(AsW + j*8*64), 16, 0, 0);
        #pragma unroll
        for (int j = 0; j < BROWS/8; j++)
            __builtin_amdgcn_global_load_lds(
                (const __attribute__((address_space(1))) void*)(Bbase + (size_t)(j*8)*K + k0),
                (__attribute__((address_space(3))) void*)(BsW + j*8*64), 16, 0, 0);
        __syncthreads();
        #pragma unroll
        for (int kk = 0; kk < 64; kk += 32){
            int cb = kk >> 3;
            bf16x8 af[4], bfr[NT];
            #pragma unroll
            for (int mt=0; mt<4; mt++)
                af[mt] = *(const bf16x8*)&As[(wave_m + mt*16 + lm)*64 + (((cb + quad) ^ (lm & 7))*8)];
            #pragma unroll
            for (int nt=0; nt<NT; nt++)
                bfr[nt] = *(const bf16x8*)&Bs[(wave_n + nt*16 + lm)*64 + (((cb + quad) ^ (lm & 7))*8)];
            #pragma unroll
            for (int mt=0; mt<4; mt++)
                #pragma unroll
                for (int nt=0; nt<NT; nt++)
                    acc[mt][nt] = __builtin_amdgcn_mfma_f32_16x16x32_bf16(af[mt], bfr[nt], acc[mt][nt], 0, 0, 0);
        }
        __syncthreads();
    }
    float* Cfo = Cf + (size_t)((NS > 1) ? blockIdx.z : 0) * (size_t)M * ldc;
    int addb = (NS == 1) || (blockIdx.z == 0);
    int crow0 = m0 + wave_m + quad * 4;
    int ccol0 = n0 + wave_n + lm;
    #pragma unroll
    for (int mt=0; mt<4; mt++){
        #pragma unroll
        for (int nt=0; nt<NT; nt++){
            int col = ccol0 + nt*16;
            if (col < N){
                float bv = addb ? bias[col] : 0.f;
                #pragma unroll
                for (int r=0; r<4; r++){
                    int row = crow0 + mt*16 + r;
                    float v = acc[mt][nt][r] + bv;
                    if (ACT == 1){
                        float t = fminf(fmaxf(v + 3.f, 0.f), 6.f);
                        v = v * t * (1.f/6.f);
                    }
                    if (OUT_BF16){
                        Cb[(size_t)row*ldc + col] = f2b(v);
                        if (DTX && col >= N - NHEADS)
                            dtaux[(size_t)row*NHEADS + (col - (N - NHEADS))] = v;
                    } else {
                        Cfo[(size_t)row*ldc + col] = v;
                    }
                }
            }
        }
    }
}

// ================================================================ 256x256 8-phase GEMM
// Measured: 61 us for M=4096,N=4096,K=1024 at grid 256 (563 TF) — on par with
// legacy, used only for fc1 (where it was measured). ONLY launch with grid==256.
template<int ACT>
__global__ __launch_bounds__(512) void gemm256_k(
    const ushort_t* __restrict__ A, const ushort_t* __restrict__ Bt,
    const float* __restrict__ bias, ushort_t* __restrict__ Cb,
    int M, int N, int K, int ldc, int nbx)
{
    __shared__ ushort_t sm[65536];          // 128 KiB
    const int tid  = threadIdx.x;
    const int lane = tid & 63, wave = tid >> 6;
    const int lm   = lane & 15, quad = lane >> 4;
    const int wm   = wave >> 2, wn = wave & 3;
    const int nwg = gridDim.x;
    const int cpx = nwg >> 3;
    const int swz = (blockIdx.x & 7)*cpx + (blockIdx.x >> 3);
    const int bx = swz % nbx, by = swz / nbx;
    const int m0 = by << 8, n0 = bx << 8;
    const int NT  = K >> 6;
    const int srow = tid >> 2;
    const int scol = (((tid & 3) ^ ((srow >> 1) & 3)) << 3);
    const ushort_t* pA = A  + (size_t)(m0 + srow)*K + scol;
    const ushort_t* pB = Bt + (size_t)(n0 + srow)*K + scol;
    const size_t rstep = (size_t)128 * K;
    const int swz8 = ((quad ^ ((lm >> 1) & 3)) << 3);
    const int aoff = (wm*128 + lm)*32 + swz8;
    const int boff = 16384 + (wn*64 + lm)*32 + swz8;

#define GL(off, src) __builtin_amdgcn_global_load_lds( \
        (const __attribute__((address_space(1))) void*)(src), \
        (__attribute__((address_space(3))) void*)(&sm[off]), 16, 0, 0)

    {
        const int d = wave*512;
        GL(d,                 pA);        GL(d + 4096,          pA + rstep);
        GL(d + 16384,         pB);        GL(d + 16384 + 4096,  pB + rstep);
        GL(d + 8192,          pA + 32);   GL(d + 8192 + 4096,   pA + 32 + rstep);
        GL(d + 24576,         pB + 32);   GL(d + 24576 + 4096,  pB + 32 + rstep);
    }
    asm volatile("s_waitcnt vmcnt(0)" ::: "memory");
    __builtin_amdgcn_sched_barrier(0);
    __builtin_amdgcn_s_barrier();

    f32x4 acc[8][4];
    #pragma unroll
    for (int i = 0; i < 8; i++)
        #pragma unroll
        for (int j = 0; j < 4; j++) acc[i][j] = (f32x4){0.f,0.f,0.f,0.f};

#define MFMA16(MH) \
    __builtin_amdgcn_s_setprio(1); \
    _Pragma("unroll") \
    for (int mt = 0; mt < 4; mt++) \
        _Pragma("unroll") \
        for (int nt = 0; nt < 4; nt++) \
            acc[(MH)*4+mt][nt] = __builtin_amdgcn_mfma_f32_16x16x32_bf16(af[mt], bf[nt], acc[(MH)*4+mt][nt], 0, 0, 0); \
    __builtin_amdgcn_s_setprio(0);

    for (int t = 0; t < NT; ++t){
        const int bo = (t & 1) << 15;
        const int nb = bo ^ 32768;
        const bool stg = (t < NT-1);
        const ushort_t* pAn = pA + (size_t)(t+1)*64;
        const ushort_t* pBn = pB + (size_t)(t+1)*64;
        bf16x8 af[4], bf[4];

        #pragma unroll
        for (int nt = 0; nt < 4; nt++) bf[nt] = *(const bf16x8*)&sm[bo + boff + nt*512];
        #pragma unroll
        for (int mt = 0; mt < 4; mt++) af[mt] = *(const bf16x8*)&sm[bo + aoff + mt*512];
        if (stg){ GL(nb + wave*512, pAn); GL(nb + 4096 + wave*512, pAn + rstep); }
        __builtin_amdgcn_s_barrier();
        asm volatile("s_waitcnt lgkmcnt(0)");
        __builtin_amdgcn_sched_barrier(0);
        MFMA16(0)
        __builtin_amdgcn_s_barrier();

        #pragma unroll
        for (int mt = 0; mt < 4; mt++) af[mt] = *(const bf16x8*)&sm[bo + aoff + 2048 + mt*512];
        if (stg){ GL(nb + 16384 + wave*512, pBn); GL(nb + 16384 + 4096 + wave*512, pBn + rstep); }
        if (stg) asm volatile("s_waitcnt vmcnt(4)" ::: "memory");
        else     asm volatile("s_waitcnt vmcnt(0)" ::: "memory");
        __builtin_amdgcn_sched_barrier(0);
        __builtin_amdgcn_s_barrier();
        asm volatile("s_waitcnt lgkmcnt(0)");
        __builtin_amdgcn_sched_barrier(0);
        MFMA16(1)
        __builtin_amdgcn_s_barrier();

        #pragma unroll
        for (int nt = 0; nt < 4; nt++) bf[nt] = *(const bf16x8*)&sm[bo + 8192 + boff + nt*512];
        #pragma unroll
        for (int mt = 0; mt < 4; mt++) af[mt] = *(const bf16x8*)&sm[bo + 8192 + aoff + 2048 + mt*512];
        if (stg){ GL(nb + 8192 + wave*512, pAn + 32); GL(nb + 8192 + 4096 + wave*512, pAn + 32 + rstep); }
        __builtin_amdgcn_s_barrier();
        asm volatile("s_waitcnt lgkmcnt(0)");
        __builtin_amdgcn_sched_barrier(0);
        MFMA16(1)
        __builtin_amdgcn_s_barrier();

        #pragma unroll
        for (int mt = 0; mt < 4; mt++) af[mt] = *(const bf16x8*)&sm[bo + 8192 + aoff + mt*512];
        if (stg){
            GL(nb + 24576 + wave*512, pBn + 32); GL(nb + 24576 + 4096 + wave*512, pBn + 32 + rstep);
            asm volatile("s_waitcnt vmcnt(4)" ::: "memory");
            __builtin_amdgcn_sched_barrier(0);
        }
        __builtin_amdgcn_s_barrier();
        asm volatile("s_waitcnt lgkmcnt(0)");
        __builtin_amdgcn_sched_barrier(0);
        MFMA16(0)
        __builtin_amdgcn_s_barrier();
    }
#undef MFMA16
#undef GL

    const int crow = m0 + wm*128 + quad*4;
    const int ccol = n0 + wn*64 + lm;
    #pragma unroll
    for (int m8 = 0; m8 < 8; m8++){
        #pragma unroll
        for (int nt = 0; nt < 4; nt++){
            int col = ccol + nt*16;
            float bv = bias[col];
            #pragma unroll
            for (int r = 0; r < 4; r++){
                int row = crow + m8*16 + r;
                float v = acc[m8][nt][r] + bv;
                if (ACT == 1){
                    float tt = fminf(fmaxf(v + 3.f, 0.f), 6.f);
                    v = v * tt * (1.f/6.f);
                }
                Cb[(size_t)row*ldc + col] = f2b(v);
            }
        }
    }
}

// ---------------- merged: f2b(x) float4-vectorized [blocks 0..4095] + W_in transpose
// W_in^T padded to DPROJ_PAD=4608 rows (zeros past DPROJ) so the in-proj GEMM
// at grid x=35 can overread B rows 4384..4479 safely.
__global__ __launch_bounds__(256) void prep_in_k(const float* __restrict__ x,
                                                 ushort_t* __restrict__ x_bf,
                                                 const float* __restrict__ W_in,
                                                 ushort_t* __restrict__ WinT){
    __shared__ ushort_t tile[32][33];
    int bid = blockIdx.x;
    if (bid < 4096){
        int idx = (bid*256 + threadIdx.x)*4;
        float4 v = *(const float4*)&x[idx];
        bf16x4 o;
        o[0] = (short)f2b(v.x); o[1] = (short)f2b(v.y);
        o[2] = (short)f2b(v.z); o[3] = (short)f2b(v.w);
        *(bf16x4*)&x_bf[idx] = o;
        return;
    }
    int id2 = bid - 4096;                   // 4608 transpose blocks (144 x 32)
    int n0 = (id2 % 144)*32, k0 = (id2 / 144)*32;
    int tx = threadIdx.x & 31, ty = threadIdx.x >> 5;
    #pragma unroll
    for (int i = 0; i < 4; i++){
        int k = k0 + ty + i*8;
        int n = n0 + tx;
        float v = (n < DPROJ) ? W_in[(size_t)k*DPROJ + n] : 0.f;
        tile[ty + i*8][tx] = f2b(v);
    }
    __syncthreads();
    #pragma unroll
    for (int i = 0; i < 4; i++)
        WinT[(size_t)(n0 + ty + i*8)*DM + k0 + tx] = tile[tx][ty + i*8];
}

// ---------------- merged: W_out / fc1 / fc2 transposes in one launch
__global__ __launch_bounds__(256) void transpose3_k(const float* __restrict__ Wout,
                                                    const float* __restrict__ fc1w,
                                                    const float* __restrict__ fc2w,
                                                    ushort_t* __restrict__ WoutT,
                                                    ushort_t* __restrict__ fc1T,
                                                    ushort_t* __restrict__ fc2T){
    __shared__ ushort_t tile[32][33];
    int bid = blockIdx.x;
    const float* W; ushort_t* Wt; int K, N, gx, id;
    if (bid < 2048){        W = Wout; Wt = WoutT; K = DI;  N = DM;  gx = 32;  id = bid; }
    else if (bid < 6144){   W = fc1w; Wt = fc1T;  K = DM;  N = DFF; gx = 128; id = bid - 2048; }
    else {                  W = fc2w; Wt = fc2T;  K = DFF; N = DM;  gx = 32;  id = bid - 6144; }
    int n0 = (id % gx)*32, k0 = (id / gx)*32;
    int tx = threadIdx.x & 31, ty = threadIdx.x >> 5;
    #pragma unroll
    for (int i = 0; i < 4; i++){
        int k = k0 + ty + i*8;
        int n = n0 + tx;
        tile[ty + i*8][tx] = f2b(W[(size_t)k*N + n]);
    }
    __syncthreads();
    #pragma unroll
    for (int i = 0; i < 4; i++)
        Wt[(size_t)(n0 + ty + i*8)*K + k0 + tx] = tile[tx][ty + i*8];
}

// ---- merged conv (LDS time-tiled) + dt-scan
// Conv blocks [0, 512): each owns an 8-row x 2304-ch output tile. Stages the
// 11 input rows (50.7 KB) into LDS ONCE (coalesced 16B/lane), keeps each
// channel-octet's conv_w (8xfloat4) + conv_b in REGISTERS across all 8 output
// rows. Read amplification 4x -> 1.375x; conv_w refetch 8x -> 1x.
// dt blocks [512, 512+512): unchanged scan (aliases the LDS array).
#define CONVROWS 8
#define CONVLROWS 11
#define CONVOCT (CONVD/8)                 // 288
#define CONVSTG (CONVLROWS*CONVOCT)       // 3168 bf16x8 vectors
#define CONVTBLKS (ROWS/CONVROWS)         // 512
__global__ __launch_bounds__(256) void conv_dt_k(const ushort_t* __restrict__ zx,
                                                 const float* __restrict__ conv_w,
                                                 const float* __restrict__ conv_b,
                                                 ushort_t* __restrict__ convb,
                                                 const float* __restrict__ dtaux,
                                                 const float* __restrict__ time_diff,
                                                 const float* __restrict__ A_log,
                                                 const float* __restrict__ dt_bias,
                                                 const float* __restrict__ time_decay,
                                                 float* __restrict__ dtH,
                                                 float* __restrict__ Acum){
    __shared__ ushort_t lds[CONVLROWS*CONVD];     // 50688 B (dt branch aliases)
    int bid = blockIdx.x;
    int tid = threadIdx.x;
    if (bid < CONVTBLKS){
        int b  = bid >> 8;                 // SEQL/CONVROWS = 256 blocks/batch
        int t0 = (bid & 255) * CONVROWS;
        // ---- stage rows t0-3 .. t0+7 (zeros for t<0, per-batch padding)
        for (int e = tid; e < CONVSTG; e += 256){
            int r  = e / CONVOCT;
            int c8 = e - r*CONVOCT;
            int t  = t0 - 3 + r;
            bf16x8 v = (bf16x8){0,0,0,0,0,0,0,0};
            if (t >= 0)
                v = *(const bf16x8*)&zx[((size_t)(b*SEQL + t))*DPROJ + DI + c8*8];
            *(bf16x8*)&lds[r*CONVD + c8*8] = v;
        }
        __syncthreads();
        // ---- compute: thread owns channel-octet(s), walks 8 output rows
        for (int oc = tid; oc < CONVOCT; oc += 256){
            float4 w[8]; float bv[8];
            #pragma unroll
            for (int j = 0; j < 8; j++){
                w[j]  = *(const float4*)&conv_w[(oc*8 + j)*4];
                bv[j] = conv_b[oc*8 + j];
            }
            #pragma unroll
            for (int dt = 0; dt < CONVROWS; dt++){
                bf16x8 x0 = *(const bf16x8*)&lds[(dt+0)*CONVD + oc*8];
                bf16x8 x1 = *(const bf16x8*)&lds[(dt+1)*CONVD + oc*8];
                bf16x8 x2 = *(const bf16x8*)&lds[(dt+2)*CONVD + oc*8];
                bf16x8 x3 = *(const bf16x8*)&lds[(dt+3)*CONVD + oc*8];
                bf16x8 o;
                #pragma unroll
                for (int j = 0; j < 8; j++){
                    float a = bv[j]
                        + b2f((ushort_t)x0[j])*w[j].x
                        + b2f((ushort_t)x1[j])*w[j].y
                        + b2f((ushort_t)x2[j])*w[j].z
                        + b2f((ushort_t)x3[j])*w[j].w;
                    o[j] = (short)f2b(silu_f(a));
                }
                *(bf16x8*)&convb[((size_t)(b*SEQL + t0 + dt))*CONVD + oc*8] = o;
            }
        }
        return;
    }
    // ---- dt / dA / cumsum scan (512 blocks)
    float* s = (float*)lds;
    int id2 = bid - CONVTBLKS;
    int c = id2 % NC;
    int h = (id2 / NC) % NHEADS;
    int b = id2 / (NC*NHEADS);
    int l = tid;
    int t = c*CHUNK + l;
    float dtr = dtaux[((size_t)(b*SEQL + t))*NHEADS + h];
    float dtv = softplus_f(dtr + dt_bias[h]);
    float A = -expf(A_log[h]);
    float dA = dtv*A - softplus_f(time_decay[h]) * time_diff[b*SEQL + t];
    dtH[((size_t)(b*NHEADS + h))*SEQL + t] = dtv;        // [h][row] layout
    s[l] = dA;
    __syncthreads();
    for (int off = 1; off < CHUNK; off <<= 1){
        float v = (l >= off) ? s[l-off] : 0.f;
        __syncthreads();
        s[l] += v;
        __syncthreads();
    }
    Acum[((size_t)(b*NHEADS + h))*SEQL + t] = s[l];
}

// -------------------- MFMA G[b,c,l,s] = C_l . B_s (64x64x128), bf16 in/out
__global__ __launch_bounds__(256) void g_mfma_k(const ushort_t* __restrict__ convb,
                                                ushort_t* __restrict__ G){
    __shared__ ushort_t As[64*136];
    __shared__ ushort_t Bs[64*136];
    int bc = blockIdx.z;
    int l0 = blockIdx.y*64, s0 = blockIdx.x*64;
    int tid = threadIdx.x;
    int lane = tid & 63, wave = tid >> 6;
    int lm = lane & 15, quad = lane >> 4;
    const ushort_t* base = convb + (size_t)bc*CHUNK*CONVD;
    #pragma unroll
    for (int i = 0; i < 4; i++){
        int e = tid + i*256;
        int r = e >> 4, k = (e & 15)*8;
        *(bf16x8*)&As[r*136 + k] = *(const bf16x8*)&base[(size_t)(l0+r)*CONVD + DI + DSTATE + k];
        *(bf16x8*)&Bs[r*136 + k] = *(const bf16x8*)&base[(size_t)(s0+r)*CONVD + DI + k];
    }
    __syncthreads();
    f32x4 acc[4];
    #pragma unroll
    for (int j=0;j<4;j++) acc[j] = (f32x4){0.f,0.f,0.f,0.f};
    #pragma unroll
    for (int kk = 0; kk < 4; kk++){
        bf16x8 af = *(const bf16x8*)&As[(wave*16+lm)*136 + kk*32 + quad*8];
        #pragma unroll
        for (int nt = 0; nt < 4; nt++){
            bf16x8 bfr = *(const bf16x8*)&Bs[(nt*16+lm)*136 + kk*32 + quad*8];
            acc[nt] = __builtin_amdgcn_mfma_f32_16x16x32_bf16(af, bfr, acc[nt], 0, 0, 0);
        }
    }
    ushort_t* g = G + (size_t)bc*CHUNK*CHUNK;
    #pragma unroll
    for (int nt = 0; nt < 4; nt++)
        #pragma unroll
        for (int r = 0; r < 4; r++)
            g[(size_t)(l0 + wave*16 + quad*4 + r)*CHUNK + s0 + nt*16 + lm] = f2b(acc[nt][r]);
}

// ---- MFMA states[b,c,h,p,n] = sum_l B[l,n]*exp(AcL-Ac[l])*dt[l]*xs[l,p]
#define RSX 264
#define RSB 72
__global__ __launch_bounds__(256) void states_mfma_k(const ushort_t* __restrict__ convb,
                                                     const float* __restrict__ dtH,
                                                     const float* __restrict__ Acum,
                                                     float* __restrict__ states){
    __shared__ ushort_t xw[64*RSX];
    __shared__ ushort_t Bt[128*RSB];
    __shared__ float Acs[CHUNK];
    __shared__ float esc[CHUNK];
    int bid = blockIdx.x;
    int h = bid % NHEADS;
    int c = (bid / NHEADS) % NC;
    int b = bid / (NHEADS*NC);
    int tid = threadIdx.x;
    int lane = tid & 63, wave = tid >> 6;
    int lm = lane & 15, quad = lane >> 4;
    Acs[tid] = Acum[((size_t)(b*NHEADS + h))*SEQL + c*CHUNK + tid];
    float dtv = dtH[((size_t)(b*NHEADS + h))*SEQL + c*CHUNK + tid];
    __syncthreads();
    // esc[l] = exp(AcL - Ac[l]) * dt[l], computed ONCE per row (was 64x/lane)
    esc[tid] = expf(Acs[CHUNK-1] - Acs[tid]) * dtv;
    __syncthreads();
    {
        const ushort_t* xg = convb + ((size_t)(b*SEQL + c*CHUNK))*CONVD + h*HD;
        #pragma unroll
        for (int j8 = 0; j8 < 8; j8++){
            int s0 = wave*64 + j8*8;
            bf16x8 pk;
            #pragma unroll
            for (int j = 0; j < 8; j++){
                int l = s0 + j;
                pk[j] = (short)f2b(esc[l] * b2f(xg[(size_t)l*CONVD + lane]));
            }
            *(bf16x8*)&xw[lane*RSX + s0] = pk;
        }
    }
    f32x4 acc[8];
    #pragma unroll
    for (int j=0;j<8;j++) acc[j] = (f32x4){0.f,0.f,0.f,0.f};
    const ushort_t* bbase = convb + ((size_t)(b*SEQL + c*CHUNK))*CONVD + DI;
    for (int l0 = 0; l0 < CHUNK; l0 += 64){
        __syncthreads();
        #pragma unroll
        for (int i = 0; i < 32; i++){
            int e = tid + i*256; int l = e >> 7, n = e & 127;
            Bt[n*RSB + l] = bbase[(size_t)(l0+l)*CONVD + n];
        }
        __syncthreads();
        #pragma unroll
        for (int kk = 0; kk < 2; kk++){
            bf16x8 af = *(const bf16x8*)&xw[(wave*16+lm)*RSX + l0 + kk*32 + quad*8];
            #pragma unroll
            for (int nt = 0; nt < 8; nt++){
                bf16x8 bfr = *(const bf16x8*)&Bt[(nt*16+lm)*RSB + kk*32 + quad*8];
                acc[nt] = __builtin_amdgcn_mfma_f32_16x16x32_bf16(af, bfr, acc[nt], 0, 0, 0);
            }
        }
    }
    float* outp = states + ((size_t)((b*NC + c)*NHEADS + h))*(HD*DSTATE);
    #pragma unroll
    for (int nt = 0; nt < 8; nt++)
        #pragma unroll
        for (int r = 0; r < 4; r++)
            outp[(size_t)(wave*16 + quad*4 + r)*DSTATE + nt*16 + lm] = acc[nt][r];
}

// ------------- inter-chunk recurrence, 16-way split over (p,n) elements
__global__ __launch_bounds__(256) void prev_scan_k(const float* __restrict__ states,
                                                   const float* __restrict__ Acum,
                                                   float* __restrict__ prev){
    int bid = blockIdx.x;                  // B*NHEADS*16
    int part = bid & 15;
    int h = (bid >> 4) & (NHEADS-1);
    int b = bid >> 9;
    int tid = threadIdx.x;
    const float* AcB = Acum + ((size_t)(b*NHEADS + h))*SEQL;
    float dec[NC];
    #pragma unroll
    for (int c = 0; c < NC; c++) dec[c] = expf(AcB[c*CHUNK + CHUNK-1]);
    #pragma unroll
    for (int j = 0; j < 2; j++){
        int e = part*512 + j*256 + tid;
        float carry = 0.f;
        #pragma unroll
        for (int c = 0; c < NC; c++){
            size_t idx = ((size_t)((b*NC + c)*NHEADS + h))*(HD*DSTATE) + e;
            prev[idx] = carry;
            carry = carry*dec[c] + states[idx];
        }
    }
}

// ===== MFMA SSD output: Y = P@(dt*xs) + (e^A C)@prev^T + D*xs  -> bf16 Ybf
#define RLX 264
#define RLP 136
__global__ __launch_bounds__(256) void y_mfma_k(const ushort_t* __restrict__ convb,
                                                const ushort_t* __restrict__ G,
                                                const float* __restrict__ Acum,
                                                const float* __restrict__ dtH,
                                                const float* __restrict__ prev,
                                                const float* __restrict__ Dp,
                                                ushort_t* __restrict__ Ybf){
    __shared__ ushort_t xdtT[64*RLX];
    __shared__ ushort_t prevs[64*RLP];
    __shared__ float Acs[CHUNK];
    __shared__ float dts[CHUNK];
    int bid = blockIdx.x;
    int h = bid % NHEADS;
    int c = (bid / NHEADS) % NC;
    int b = bid / (NHEADS*NC);
    int tid = threadIdx.x;
    int lane = tid & 63, wave = tid >> 6;
    int lm = lane & 15, quad = lane >> 4;

    Acs[tid] = Acum[((size_t)(b*NHEADS + h))*SEQL + c*CHUNK + tid];
    dts[tid] = dtH[((size_t)(b*NHEADS + h))*SEQL + c*CHUNK + tid];
    {
        const float* pv = prev + ((size_t)((b*NC + c)*NHEADS + h))*(HD*DSTATE);
        #pragma unroll
        for (int i = 0; i < 32; i++){
            int e = tid + i*256; int p = e >> 7, n = e & 127;
            prevs[p*RLP + n] = f2b(pv[e]);
        }
    }
    __syncthreads();
    {
        const ushort_t* xg = convb + ((size_t)(b*SEQL + c*CHUNK))*CONVD + h*HD;
        #pragma unroll
        for (int j8 = 0; j8 < 8; j8++){
            int s0 = wave*64 + j8*8;
            bf16x8 pk;
            #pragma unroll
            for (int j = 0; j < 8; j++){
                int l = s0 + j;
                pk[j] = (short)f2b(b2f(xg[(size_t)l*CONVD + lane]) * dts[l]);
            }
            *(bf16x8*)&xdtT[lane*RLX + s0] = pk;
        }
    }
    __syncthreads();

    int   lrow[4];  float Alr[4], eAlr[4];
    #pragma unroll
    for (int mt = 0; mt < 4; mt++){
        lrow[mt] = (mt*4 + wave)*16 + lm;
        Alr[mt]  = Acs[lrow[mt]];
        eAlr[mt] = expf(Alr[mt]);
    }
    const ushort_t* Gbase = G + ((size_t)(b*NC + c))*(CHUNK*CHUNK);

    f32x4 acc[4][4];
    #pragma unroll
    for (int i=0;i<4;i++)
        #pragma unroll
        for (int j=0;j<4;j++) acc[i][j] = (f32x4){0.f,0.f,0.f,0.f};

    for (int ks = 0; ks < 8; ks++){
        bf16x8 bfr[4];
        #pragma unroll
        for (int nt = 0; nt < 4; nt++)
            bfr[nt] = *(const bf16x8*)&xdtT[(nt*16+lm)*RLX + ks*32 + quad*8];
        #pragma unroll
        for (int mt = 0; mt < 4; mt++){
            int rblk = mt*4 + wave;
            int nst = rblk/2 + 1;
            if (ks < nst){
                int sbase = ks*32 + quad*8;
                bf16x8 g8 = *(const bf16x8*)&Gbase[(size_t)lrow[mt]*CHUNK + sbase];
                const float4* A4 = (const float4*)(&Acs[sbase]);
                float4 a0 = A4[0], a1 = A4[1];
                float Al = Alr[mt]; int l = lrow[mt];
                float pv[8];
                pv[0] = (sbase+0 <= l) ? b2f((ushort_t)g8[0])*expf(Al - a0.x) : 0.f;
                pv[1] = (sbase+1 <= l) ? b2f((ushort_t)g8[1])*expf(Al - a0.y) : 0.f;
                pv[2] = (sbase+2 <= l) ? b2f((ushort_t)g8[2])*expf(Al - a0.z) : 0.f;
                pv[3] = (sbase+3 <= l) ? b2f((ushort_t)g8[3])*expf(Al - a0.w) : 0.f;
                pv[4] = (sbase+4 <= l) ? b2f((ushort_t)g8[4])*expf(Al - a1.x) : 0.f;
                pv[5] = (sbase+5 <= l) ? b2f((ushort_t)g8[5])*expf(Al - a1.y) : 0.f;
                pv[6] = (sbase+6 <= l) ? b2f((ushort_t)g8[6])*expf(Al - a1.z) : 0.f;
                pv[7] = (sbase+7 <= l) ? b2f((ushort_t)g8[7])*expf(Al - a1.w) : 0.f;
                bf16x8 af;
                #pragma unroll
                for (int j = 0; j < 8; j++) af[j] = (short)f2b(pv[j]);
                #pragma unroll
                for (int nt = 0; nt < 4; nt++)
                    acc[mt][nt] = __builtin_amdgcn_mfma_f32_16x16x32_bf16(af, bfr[nt], acc[mt][nt], 0, 0, 0);
            }
        }
    }
    for (int kc = 0; kc < 4; kc++){
        bf16x8 bfr[4];
        #pragma unroll
        for (int nt = 0; nt < 4; nt++)
            bfr[nt] = *(const bf16x8*)&prevs[(nt*16+lm)*RLP + kc*32 + quad*8];
        #pragma unroll
        for (int mt = 0; mt < 4; mt++){
            int rowg = b*SEQL + c*CHUNK + lrow[mt];
            bf16x8 c8 = *(const bf16x8*)&convb[(size_t)rowg*CONVD + DI + DSTATE + kc*32 + quad*8];
            float e = eAlr[mt];
            bf16x8 af;
            #pragma unroll
            for (int j = 0; j < 8; j++) af[j] = (short)f2b(e * b2f((ushort_t)c8[j]));
            #pragma unroll
            for (int nt = 0; nt < 4; nt++)
                acc[mt][nt] = __builtin_amdgcn_mfma_f32_16x16x32_bf16(af, bfr[nt], acc[mt][nt], 0, 0, 0);
        }
    }
    float Dv = Dp[h];
    #pragma unroll
    for (int mt = 0; mt < 4; mt++){
        int l0 = (mt*4 + wave)*16 + quad*4;
        #pragma unroll
        for (int nt = 0; nt < 4; nt++){
            int p = nt*16 + lm;
            #pragma unroll
            for (int r = 0; r < 4; r++){
                int rowg = b*SEQL + c*CHUNK + l0 + r;
                float xs = b2f(convb[(size_t)rowg*CONVD + h*HD + p]);
                Ybf[(size_t)rowg*DI + h*HD + p] = f2b(acc[mt][nt][r] + Dv*xs);
            }
        }
    }
}

// ------------------------------- y = Y*silu(z); RMSNorm; * rms_w ; -> bf16
__global__ __launch_bounds__(256) void gate_rms_k(const ushort_t* __restrict__ Yb,
                                                  const ushort_t* __restrict__ zx,
                                                  const float* __restrict__ rms_w,
                                                  ushort_t* __restrict__ yn){
    __shared__ float red[4];
    __shared__ float scale_s;
    int row = blockIdx.x; int tid = threadIdx.x;
    float v[8]; float ss = 0.f;
    #pragma unroll
    for (int i = 0; i < 8; i++){
        int d = tid + i*256;
        float g = b2f(Yb[(size_t)row*DI + d]) * silu_f(b2f(zx[(size_t)row*DPROJ + d]));
        v[i] = g; ss += g*g;
    }
    #pragma unroll
    for (int off = 32; off > 0; off >>= 1) ss += __shfl_down(ss, off);
    int lane = tid & 63, wid = tid >> 6;
    if (lane == 0) red[wid] = ss;
    __syncthreads();
    if (tid == 0) scale_s = rsqrtf((red[0]+red[1]+red[2]+red[3])*(1.f/DI) + 1e-12f);
    __syncthreads();
    float sc = scale_s;
    #pragma unroll
    for (int i = 0; i < 8; i++){
        int d = tid + i*256;
        yn[(size_t)row*DI + d] = f2b(v[i]*sc*rms_w[d]);
    }
}

// -------- LN(a + a2 + resid_f32) -> bf16 only (mid LN)
__global__ __launch_bounds__(256) void ln_hbf_k(const float* __restrict__ a,
                                                const float* __restrict__ a2,
                                                const float* __restrict__ resid,
                                                const float* __restrict__ g,
                                                const float* __restrict__ bw,
                                                ushort_t* __restrict__ bfout){
    __shared__ float redA[4], redB[4];
    __shared__ float mu_s, rs_s;
    int row = blockIdx.x; int tid = threadIdx.x;
    float u[4]; float s = 0.f, s2 = 0.f;
    #pragma unroll
    for (int i = 0; i < 4; i++){
        int d = tid + i*256;
        float val = a[(size_t)row*DM + d] + a2[(size_t)row*DM + d] + resid[(size_t)row*DM + d];
        u[i] = val; s += val; s2 += val*val;
    }
    #pragma unroll
    for (int off = 32; off > 0; off >>= 1){
        s  += __shfl_down(s,  off);
        s2 += __shfl_down(s2, off);
    }
    int lane = tid & 63, wid = tid >> 6;
    if (lane == 0){ redA[wid] = s; redB[wid] = s2; }
    __syncthreads();
    if (tid == 0){
        float S  = redA[0]+redA[1]+redA[2]+redA[3];
        float S2 = redB[0]+redB[1]+redB[2]+redB[3];
        float mu = S*(1.f/DM);
        float var = S2*(1.f/DM) - mu*mu;
        mu_s = mu; rs_s = rsqrtf(var + 1e-12f);
    }
    __syncthreads();
    float mu = mu_s, rs = rs_s;
    #pragma unroll
    for (int i = 0; i < 4; i++){
        int d = tid + i*256;
        bfout[(size_t)row*DM + d] = f2b((u[i]-mu)*rs*g[d] + bw[d]);
    }
}

// -------- final LN(a + a2 + resid_bf16) -> fp32 d_out; extra blocks copy td
__global__ __launch_bounds__(256) void ln_final_k(const float* __restrict__ a,
                                                  const float* __restrict__ a2,
                                                  const ushort_t* __restrict__ residb,
                                                  const float* __restrict__ g,
                                                  const float* __restrict__ bw,
                                                  float* __restrict__ outp,
                                                  const float* __restrict__ td){
    __shared__ float redA[4], redB[4];
    __shared__ float mu_s, rs_s;
    int row = blockIdx.x; int tid = threadIdx.x;
    if (row >= ROWS){
        int idx = (row - ROWS)*256 + tid;
        outp[(size_t)ROWS*DM + idx] = td[idx];
        return;
    }
    float u[4]; float s = 0.f, s2 = 0.f;
    #pragma unroll
    for (int i = 0; i < 4; i++){
        int d = tid + i*256;
        float val = a[(size_t)row*DM + d] + a2[(size_t)row*DM + d] + b2f(residb[(size_t)row*DM + d]);
        u[i] = val; s += val; s2 += val*val;
    }
    #pragma unroll
    for (int off = 32; off > 0; off >>= 1){
        s  += __shfl_down(s,  off);
        s2 += __shfl_down(s2, off);
    }
    int lane = tid & 63, wid = tid >> 6;
    if (lane == 0){ redA[wid] = s; redB[wid] = s2; }
    __syncthreads();
    if (tid == 0){
        float S  = redA[0]+redA[1]+redA[2]+redA[3];
        float S2 = redB[0]+redB[1]+redB[2]+redB[3];
        float mu = S*(1.f/DM);
        float var = S2*(1.f/DM) - mu*mu;
        mu_s = mu; rs_s = rsqrtf(var + 1e-12f);
    }
    __syncthreads();
    float mu = mu_s, rs = rs_s;
    #pragma unroll
    for (int i = 0; i < 4; i++){
        int d = tid + i*256;
        outp[(size_t)row*DM + d] = (u[i]-mu)*rs*g[d] + bw[d];
    }
}

extern "C" void kernel_launch(void* const* d_in, const int* in_sizes, int n_in,
                              void* d_out, int out_size, void* d_ws, size_t ws_size,
                              hipStream_t stream){
    const float* x         = (const float*)d_in[0];
    const float* time_diff = (const float*)d_in[1];
    const float* W_in      = (const float*)d_in[2];
    const float* b_in      = (const float*)d_in[3];
    const float* conv_w    = (const float*)d_in[4];
    const float* conv_b    = (const float*)d_in[5];
    const float* A_log     = (const float*)d_in[6];
    const float* dt_bias   = (const float*)d_in[7];
    const float* Dp        = (const float*)d_in[8];
    const float* time_dec  = (const float*)d_in[9];
    const float* rms_w     = (const float*)d_in[10];
    const float* W_out     = (const float*)d_in[11];
    const float* b_out     = (const float*)d_in[12];
    const float* ln_g      = (const float*)d_in[13];
    const float* ln_b      = (const float*)d_in[14];
    const float* fc1_w     = (const float*)d_in[15];
    const float* fc1_b     = (const float*)d_in[16];
    const float* fc2_w     = (const float*)d_in[17];
    const float* fc2_b     = (const float*)d_in[18];
    const float* ln2_g     = (const float*)d_in[19];
    const float* ln2_b     = (const float*)d_in[20];

    float* ws = (float*)d_ws;
    float* zx    = ws;                       // region1: 17,956,864 f
    float* convb = zx    + 17956864;         // region2:  9,437,184 f
    float* dtH   = convb + 9437184;
    float* Acum  = dtH   + 131072;
    float* r4    = Acum  + 131072;           // region4:  8,388,608 f
    float* r5    = r4    + 8388608;          // region5:  9,437,184 f
    float* ybreg = r5    + 9437184;          // region6:  4,194,304 f
    // region1 aliases
    ushort_t* zx_bf  = (ushort_t*)zx;                 // steps 2-8
    float*    dtaux  = zx + 10600000;                 // steps 2-3
    ushort_t* mid_bf = (ushort_t*)zx;                 // steps 12-13 (zx dead)
    ushort_t* h_bf   = (ushort_t*)(zx + 8388608);     // steps 11-14 (zx dead)
    // region2 aliases
    ushort_t* convb_bf = (ushort_t*)convb;            // steps 3-7
    float* outPa  = convb;                            // steps 10-11 (convb dead)
    // region4 aliases
    ushort_t* x_bf  = (ushort_t*)r4;                  // steps 1-2
    ushort_t* WinT  = (ushort_t*)(r4 + 2097152);      // steps 1-2 (4608x1024 bf16)
    ushort_t* WoutT = (ushort_t*)(r4 + 4194304);      // steps 9-10
    float* fc2Pa = r4;                                // steps 13-14
    // region5 aliases
    ushort_t* Gb   = (ushort_t*)r5;                   // steps 4-7
    float* stat = r5 + 1048576;                       // steps 5-6
    float* prev = stat + 4194304;                     // steps 6-7
    ushort_t* yn_bf = (ushort_t*)r5;                  // steps 8-10 (G/stat dead)
    ushort_t* fc1T  = (ushort_t*)(r5 + 4194304);      // steps 9-12 (stat/prev dead)
    ushort_t* fc2T  = (ushort_t*)(r5 + 6291456);      // steps 9-13 (prev dead)
    // region6
    ushort_t* Ybf = (ushort_t*)ybreg;                 // steps 7-8
    float* outp   = (float*)d_out;

    // 1. f2b(x) (float4-vectorized) + W_in^T (zero-padded to 4608 rows)
    prep_in_k<<<4096 + 4608, 256, 0, stream>>>(x, x_bf, W_in, WinT);
    // 2. in-proj (M=4096,N=4384,K=1024): legacy single launch, grid 35x32 = 1120
    //    blocks (4-5/CU), DTX sidecar, XCD swizzle.
    mfma_gemm_k<0,1,128,1,1><<<dim3(35, ROWS/128), 256, 0, stream>>>(
        x_bf, WinT, b_in, nullptr, zx_bf, dtaux, ROWS, DPROJ, DM, DPROJ);
    // 3. conv+SiLU (LDS time-tiled, 512 blocks) + dt/dA/cumsum scan (512 blocks)
    conv_dt_k<<<CONVTBLKS + BATCH*NHEADS*NC, 256, 0, stream>>>(zx_bf, conv_w, conv_b, convb_bf,
                                                               dtaux, time_diff, A_log, dt_bias, time_dec, dtH, Acum);
    // 4. G = C @ B^T (MFMA, bf16)
    g_mfma_k<<<dim3(4,4,BATCH*NC), 256, 0, stream>>>(convb_bf, Gb);
    // 5. per-chunk states (MFMA; esc[] precomputed once per row)
    states_mfma_k<<<BATCH*NC*NHEADS, 256, 0, stream>>>(convb_bf, dtH, Acum, stat);
    // 6. inter-chunk scan (1024 blocks)
    prev_scan_k<<<BATCH*NHEADS*16, 256, 0, stream>>>(stat, Acum, prev);
    // 7. MFMA SSD output -> bf16 Y
    y_mfma_k<<<BATCH*NC*NHEADS, 256, 0, stream>>>(convb_bf, Gb, Acum, dtH, prev, Dp, Ybf);
    // 8. gate + RMSNorm -> bf16 yn
    gate_rms_k<<<ROWS, 256, 0, stream>>>(Ybf, zx_bf, rms_w, yn_bf);
    // 9. W_out / fc1 / fc2 transposes (merged)
    transpose3_k<<<10240, 256, 0, stream>>>(W_out, fc1_w, fc2_w, WoutT, fc1T, fc2T);
    // 10. out-proj split-K=2 (M=4096,N=1024,K=2048): legacy
    mfma_gemm_k<0,0,64,2,0><<<dim3(DM/64, ROWS/128, 2), 256, 0, stream>>>(yn_bf, WoutT, b_out, outPa, nullptr, nullptr, ROWS, DM, DI, DM);
    // 11. h = LN(Pa + Pb + x) -> bf16 only
    ln_hbf_k<<<ROWS, 256, 0, stream>>>(outPa, outPa + (size_t)ROWS*DM, x, ln_g, ln_b, h_bf);
    // 12. fc1 + hardswish -> bf16 mid (M=4096,N=4096,K=1024): 8-phase, grid 256
    gemm256_k<1><<<256, 512, 0, stream>>>(h_bf, fc1T, fc1_b, mid_bf,
                                          ROWS, DFF, DM, DFF, 16);
    // 13. fc2 split-K=2 (M=4096,N=1024,K=4096): legacy
    mfma_gemm_k<0,0,64,2,0><<<dim3(DM/64, ROWS/128, 2), 256, 0, stream>>>(mid_bf, fc2T, fc2_b, fc2Pa, nullptr, nullptr, ROWS, DM, DFF, DM);
    // 14. out = LN(Pa + Pb + h_bf) + td passthrough (merged)
    ln_final_k<<<ROWS + ROWS/256, 256, 0, stream>>>(fc2Pa, fc2Pa + (size_t)ROWS*DM, h_bf, ln2_g, ln2_b, outp, time_diff);
}